// Round 1
// baseline (276.427 us; speedup 1.0000x reference)
//
#include <hip/hip_runtime.h>
#include <math.h>

typedef _Float16 f16;
typedef _Float16 f16x4 __attribute__((ext_vector_type(4)));
typedef _Float16 f16x8 __attribute__((ext_vector_type(8)));
typedef float f32x4 __attribute__((ext_vector_type(4)));
typedef unsigned int u32;

#define D_MODEL 1024
#define NHEADS 16
#define DHEAD 64
#define LQ 2048
#define LKK 2048
#define BB 2

static __device__ __forceinline__ void gload16(const void* g, void* l) {
  __builtin_amdgcn_global_load_lds(
      (const __attribute__((address_space(1))) u32*)g,
      (__attribute__((address_space(3))) u32*)l, 16, 0, 0);
}

// ---------------- prep kernels ----------------

// mask dtype detection: bool(1B) vs int32 vs float32 storage of 0/1 values
__global__ void k_detect_mask(const unsigned char* raw, int* flag) {
  __shared__ int o1s, o2s;
  if (threadIdx.x == 0) { o1s = 0; o2s = 0; }
  __syncthreads();
  int o1 = 0, o2 = 0;
  for (int i = threadIdx.x; i < BB * LKK; i += blockDim.x) {
    unsigned char vv = raw[i];
    if ((i & 3) && vv) o1 = 1;                 // nonzero off-aligned byte
    if (((i & 3) == 2) && vv == 0x80u) o2 = 1; // fp32 1.0f signature
  }
  if (o1) atomicOr(&o1s, 1);
  if (o2) atomicOr(&o2s, 1);
  __syncthreads();
  if (threadIdx.x == 0) *flag = o1s ? (o2s ? 2 : 1) : 0; // 0=int32,1=bool,2=f32
}

__global__ void k_convert_mask(const void* raw, const int* flag, unsigned char* m8) {
  int i = blockIdx.x * blockDim.x + threadIdx.x;
  if (i >= BB * LKK) return;
  int f = *flag;
  unsigned char v;
  if (f == 0)      v = (((const int*)raw)[i] != 0);
  else if (f == 1) v = (((const unsigned char*)raw)[i] != 0);
  else             v = (((const float*)raw)[i] != 0.0f);
  m8[i] = v;
}

// bias table: tab[h][n] = rel_emb[bucket(n)][h], n = clamp(q-k,0,2047)
__global__ void k_build_bias(const float* __restrict__ rel_emb, float* __restrict__ tab) {
  int n = blockIdx.x * blockDim.x + threadIdx.x;
  if (n >= 2048) return;
  int bucket;
  if (n < 16) bucket = n;
  else {
    float t = logf((float)n / 16.0f + 1e-9f);
    t = t / 2.0794415416798357f; // log(8.0) in fp32, matching jax op order
    t = t * 16.0f;
    bucket = 16 + (int)t;        // trunc toward zero == astype(int32)
    if (bucket > 31) bucket = 31;
  }
  for (int h = 0; h < NHEADS; ++h)
    tab[h * 2048 + n] = rel_emb[bucket * NHEADS + h];
}

__global__ void k_cvt(const float* __restrict__ s, f16* __restrict__ d, int n4) {
  int i = blockIdx.x * blockDim.x + threadIdx.x;
  if (i >= n4) return;
  float4 v = ((const float4*)s)[i];
  f16x4 o;
  o[0] = (f16)v.x; o[1] = (f16)v.y; o[2] = (f16)v.z; o[3] = (f16)v.w;
  ((f16x4*)d)[i] = o;
}

// ---------------- GEMM: C = A[M,K] * B[N,K]^T, f16 in, fp32 accum ----------------
// EPI 0: scatter f16 into [B,H,L,64] head layout.  EPI 1: fp32 row-major [M][N].
template <int EPI>
__global__ void __launch_bounds__(256, 2)
k_gemm_bt(const f16* __restrict__ A, const f16* __restrict__ Bm,
          void* __restrict__ C, int M, int N, int K) {
  __shared__ __align__(16) f16 sA[128 * 32];
  __shared__ __align__(16) f16 sB[128 * 32];
  const int t = threadIdx.x;
  const int w = t >> 6, lane = t & 63;
  const int lg = lane >> 4, lc = lane & 15;
  const int wr = w >> 1, wc = w & 1;
  const long row0 = (long)blockIdx.x * 128;
  const long col0 = (long)blockIdx.y * 128;
  f32x4 acc[4][4] = {};

  for (int kk = 0; kk < K; kk += 32) {
#pragma unroll
    for (int it = 0; it < 2; ++it) {
      int ch = t + it * 256;          // 512 chunks of 16B over [128][32]
      int r = ch >> 2, kg = ch & 3;
      gload16(A + (row0 + r) * (long)K + kk + kg * 8, (char*)sA + ch * 16);
      gload16(Bm + (col0 + r) * (long)K + kk + kg * 8, (char*)sB + ch * 16);
    }
    __syncthreads();
    f16x8 af[4], bf[4];
#pragma unroll
    for (int i = 0; i < 4; ++i)
      af[i] = *(const f16x8*)&sA[(wr * 64 + i * 16 + lc) * 32 + lg * 8];
#pragma unroll
    for (int j = 0; j < 4; ++j)
      bf[j] = *(const f16x8*)&sB[(wc * 64 + j * 16 + lc) * 32 + lg * 8];
#pragma unroll
    for (int i = 0; i < 4; ++i)
#pragma unroll
      for (int j = 0; j < 4; ++j)
        acc[i][j] = __builtin_amdgcn_mfma_f32_16x16x32_f16(af[i], bf[j], acc[i][j], 0, 0, 0);
    __syncthreads();
  }

#pragma unroll
  for (int i = 0; i < 4; ++i)
#pragma unroll
    for (int j = 0; j < 4; ++j)
#pragma unroll
      for (int r = 0; r < 4; ++r) {
        long row = row0 + wr * 64 + i * 16 + lg * 4 + r;  // C/D: row=(l>>4)*4+reg
        long col = col0 + wc * 64 + j * 16 + lc;          //      col=l&15
        float v = acc[i][j][r];
        if (EPI == 0) {
          long b = row >> 11, l = row & 2047;
          long h = col >> 6, d = col & 63;
          ((f16*)C)[(((b * NHEADS + h) * LQ) + l) * DHEAD + d] = (f16)v;
        } else {
          ((float*)C)[row * (long)N + col] = v;
        }
      }
}

// ---------------- flash attention per (b,h,64 q rows) ----------------
__global__ void __launch_bounds__(256, 2)
k_attn(const f16* __restrict__ QH, const f16* __restrict__ KH, const f16* __restrict__ VH,
       const float* __restrict__ BIAS, const unsigned char* __restrict__ M8,
       f16* __restrict__ O16) {
  __shared__ __align__(16) f16 sQ[64 * 64];
  __shared__ __align__(16) f16 sK[64 * 64];
  __shared__ __align__(16) f16 sVT[64 * 64];
  __shared__ __align__(16) f16 sP[4][16 * 64];
  __shared__ __align__(16) float sBias[2048];
  __shared__ __align__(16) unsigned char sMask[2048];

  const int qt = blockIdx.x;          // 0..31
  const int bh = blockIdx.y;          // 0..31
  const int b = bh >> 4, h = bh & 15;
  const int t = threadIdx.x, w = t >> 6, lane = t & 63;
  const int lg = lane >> 4, lc = lane & 15;
  const size_t base = (size_t)bh * LKK * DHEAD;

  // stage Q (XOR-swizzled via pre-swizzled global source), bias row, mask
#pragma unroll
  for (int it = 0; it < 2; ++it) {
    int ch = t + it * 256;
    int r = ch >> 3;
    int grp = (ch & 7) ^ (r & 7);
    gload16(QH + base + ((size_t)(qt * 64 + r)) * DHEAD + grp * 8, (char*)sQ + ch * 16);
    gload16(BIAS + h * 2048 + ch * 4, (char*)sBias + ch * 16);
  }
  if (t < 128) gload16(M8 + b * LKK + t * 16, (char*)sMask + t * 16);
  __syncthreads();

  // hoist Q A-frags (reused over all 32 kv tiles)
  f16x8 qa[2];
  {
    int q = 16 * w + lc;
#pragma unroll
    for (int ks = 0; ks < 2; ++ks)
      qa[ks] = *(const f16x8*)((const char*)sQ +
                ((q * 128 + ks * 64 + lg * 16) ^ ((q & 7) << 4)));
  }
  float m_r[4], l_r[4];
  f32x4 accO[4] = {};
#pragma unroll
  for (int r = 0; r < 4; ++r) { m_r[r] = -1e30f; l_r[r] = 0.f; }

  for (int kt = 0; kt < LKK / 64; ++kt) {
    // stage K tile (swizzled gload) and V^T (reg transpose, swizzled)
#pragma unroll
    for (int it = 0; it < 2; ++it) {
      int ch = t + it * 256;
      int r = ch >> 3;
      int grp = (ch & 7) ^ (r & 7);
      gload16(KH + base + ((size_t)(kt * 64 + r)) * DHEAD + grp * 8, (char*)sK + ch * 16);
    }
#pragma unroll
    for (int it = 0; it < 2; ++it) {
      int ch = t + it * 256;
      int kr = ch & 63;           // k row (spread across lanes -> conflict-free LDS writes)
      int dg = ch >> 6;           // d group
      const uint4 vv = *(const uint4*)(VH + base + ((size_t)(kt * 64 + kr)) * DHEAD + dg * 8);
      const f16* pv = (const f16*)&vv;
#pragma unroll
      for (int e = 0; e < 8; ++e) {
        int d = dg * 8 + e;
        *(f16*)((char*)sVT + ((d * 128 + kr * 2) ^ ((d & 7) << 4))) = pv[e];
      }
    }
    __syncthreads();

    // S = Q * Ktile^T : wave w owns q rows 16w..16w+15, all 64 k
    f32x4 s[4] = {};
#pragma unroll
    for (int ks = 0; ks < 2; ++ks) {
#pragma unroll
      for (int j = 0; j < 4; ++j) {
        int krow = 16 * j + lc;
        f16x8 kb = *(const f16x8*)((const char*)sK +
                    ((krow * 128 + ks * 64 + lg * 16) ^ ((krow & 7) << 4)));
        s[j] = __builtin_amdgcn_mfma_f32_16x16x32_f16(qa[ks], kb, s[j], 0, 0, 0);
      }
    }

    // scale + bias + mask + online softmax
#pragma unroll
    for (int r = 0; r < 4; ++r) {
      int qg = qt * 64 + 16 * w + lg * 4 + r;
      float mx = -1e30f;
#pragma unroll
      for (int j = 0; j < 4; ++j) {
        int kg = kt * 64 + 16 * j + lc;
        int n = qg - kg; if (n < 0) n = 0;
        float sv = s[j][r] * 0.125f + sBias[n];
        if (!sMask[kg]) sv = -1e9f;
        s[j][r] = sv;
        mx = fmaxf(mx, sv);
      }
#pragma unroll
      for (int sh = 1; sh < 16; sh <<= 1) mx = fmaxf(mx, __shfl_xor(mx, sh));
      float mnew = fmaxf(m_r[r], mx);
      float alpha = __expf(m_r[r] - mnew);
      m_r[r] = mnew;
      float rs = 0.f;
#pragma unroll
      for (int j = 0; j < 4; ++j) {
        float p = __expf(s[j][r] - mnew);
        s[j][r] = p;
        rs += p;
      }
#pragma unroll
      for (int sh = 1; sh < 16; sh <<= 1) rs += __shfl_xor(rs, sh);
      l_r[r] = l_r[r] * alpha + rs;
#pragma unroll
      for (int jf = 0; jf < 4; ++jf) accO[jf][r] *= alpha;
    }

    // P -> LDS (swizzled, wave-private) then PV MFMAs
    {
      char* myP = (char*)&sP[w][0];
#pragma unroll
      for (int j = 0; j < 4; ++j)
#pragma unroll
        for (int r = 0; r < 4; ++r) {
          int prow = lg * 4 + r, pcol = 16 * j + lc;
          *(f16*)(myP + ((prow * 128 + pcol * 2) ^ ((prow & 7) << 4))) = (f16)s[j][r];
        }
      asm volatile("s_waitcnt lgkmcnt(0)" ::: "memory");
      __builtin_amdgcn_sched_barrier(0);
#pragma unroll
      for (int ks = 0; ks < 2; ++ks) {
        f16x8 pa = *(const f16x8*)(myP + ((lc * 128 + ks * 64 + lg * 16) ^ ((lc & 7) << 4)));
#pragma unroll
        for (int jf = 0; jf < 4; ++jf) {
          int drow = 16 * jf + lc;
          f16x8 vb = *(const f16x8*)((const char*)sVT +
                      ((drow * 128 + ks * 64 + lg * 16) ^ ((drow & 7) << 4)));
          accO[jf] = __builtin_amdgcn_mfma_f32_16x16x32_f16(pa, vb, accO[jf], 0, 0, 0);
        }
      }
    }
    __syncthreads();
  }

  // normalize + store to [B, L, H*64] fp16 (ready for final GEMM)
#pragma unroll
  for (int jf = 0; jf < 4; ++jf)
#pragma unroll
    for (int r = 0; r < 4; ++r) {
      int qg = qt * 64 + 16 * w + lg * 4 + r;
      float ov = accO[jf][r] / l_r[r];
      O16[((size_t)b * LQ + qg) * D_MODEL + h * DHEAD + 16 * jf + lc] = (f16)ov;
    }
}

// ---------------- launch ----------------
extern "C" void kernel_launch(void* const* d_in, const int* in_sizes, int n_in,
                              void* d_out, int out_size, void* d_ws, size_t ws_size,
                              hipStream_t stream) {
  (void)in_sizes; (void)n_in; (void)out_size; (void)ws_size;
  const float* q   = (const float*)d_in[0];
  const float* k   = (const float*)d_in[1];
  const float* v   = (const float*)d_in[2];
  const void*  msk = d_in[3];
  const float* Wq  = (const float*)d_in[4];
  const float* Wk  = (const float*)d_in[5];
  const float* Wv  = (const float*)d_in[6];
  const float* Wo  = (const float*)d_in[7];
  const float* rel = (const float*)d_in[8];

  char* ws = (char*)d_ws;
  const size_t SL = (size_t)8 << 20;       // 8 MiB slabs
  f16* Xq  = (f16*)(ws + 0 * SL);
  f16* Xk  = (f16*)(ws + 1 * SL);
  f16* Xv  = (f16*)(ws + 2 * SL);
  f16* QHp = (f16*)(ws + 3 * SL);
  f16* KHp = (f16*)(ws + 0 * SL);          // reuses Xq after proj-q
  f16* VHp = (f16*)(ws + 1 * SL);          // reuses Xk after proj-k
  f16* O16 = (f16*)(ws + 2 * SL);          // reuses Xv after attn input consumed
  f16* W16 = (f16*)(ws + 4 * SL);          // 4 x 1M f16
  float* BIAS = (float*)(ws + 5 * SL);
  int* FLAG = (int*)(ws + 5 * SL + (128 << 10));
  unsigned char* M8 = (unsigned char*)(ws + 5 * SL + (128 << 10) + 64);

  k_detect_mask<<<1, 256, 0, stream>>>((const unsigned char*)msk, FLAG);
  k_convert_mask<<<(BB * LKK + 255) / 256, 256, 0, stream>>>(msk, FLAG, M8);
  k_build_bias<<<(2048 + 255) / 256, 256, 0, stream>>>(rel, BIAS);

  const int NQ4 = BB * LQ * D_MODEL / 4;   // 1048576
  const int NW4 = D_MODEL * D_MODEL / 4;   // 262144
  k_cvt<<<(NQ4 + 255) / 256, 256, 0, stream>>>(q, Xq, NQ4);
  k_cvt<<<(NQ4 + 255) / 256, 256, 0, stream>>>(k, Xk, NQ4);
  k_cvt<<<(NQ4 + 255) / 256, 256, 0, stream>>>(v, Xv, NQ4);
  k_cvt<<<(NW4 + 255) / 256, 256, 0, stream>>>(Wq, W16 + 0 * 1048576, NW4);
  k_cvt<<<(NW4 + 255) / 256, 256, 0, stream>>>(Wk, W16 + 1 * 1048576, NW4);
  k_cvt<<<(NW4 + 255) / 256, 256, 0, stream>>>(Wv, W16 + 2 * 1048576, NW4);
  k_cvt<<<(NW4 + 255) / 256, 256, 0, stream>>>(Wo, W16 + 3 * 1048576, NW4);

  dim3 gg(32, 8), tb(256);
  k_gemm_bt<0><<<gg, tb, 0, stream>>>(Xq, W16 + 0 * 1048576, QHp, 4096, 1024, 1024);
  k_gemm_bt<0><<<gg, tb, 0, stream>>>(Xk, W16 + 1 * 1048576, KHp, 4096, 1024, 1024);
  k_gemm_bt<0><<<gg, tb, 0, stream>>>(Xv, W16 + 2 * 1048576, VHp, 4096, 1024, 1024);
  k_attn<<<dim3(32, 32), tb, 0, stream>>>(QHp, KHp, VHp, BIAS, M8, O16);
  k_gemm_bt<1><<<gg, tb, 0, stream>>>(O16, W16 + 3 * 1048576, d_out, 4096, 1024, 1024);
}

// Round 3
// 164.985 us; speedup vs baseline: 1.6755x; 1.6755x over previous
//
#include <hip/hip_runtime.h>
#include <math.h>

typedef _Float16 f16;
typedef __fp16 h16x2 __attribute__((ext_vector_type(2)));
typedef _Float16 f16x4 __attribute__((ext_vector_type(4)));
typedef _Float16 f16x8 __attribute__((ext_vector_type(8)));
typedef float f32x4 __attribute__((ext_vector_type(4)));
typedef float f32x16 __attribute__((ext_vector_type(16)));
typedef unsigned int u32;

#define D_MODEL 1024
#define NHEADS 16
#define DHEAD 64
#define LQ 2048
#define LKK 2048
#define BB 2
#define LOG2E 1.4426950408889634f

static __device__ __forceinline__ void gload16(const void* g, void* l) {
  __builtin_amdgcn_global_load_lds(
      (const __attribute__((address_space(1))) u32*)g,
      (__attribute__((address_space(3))) u32*)l, 16, 0, 0);
}
// raw v_exp_f32 (2^x); avoids llvm.exp2 denormal-fixup sequence. s_nop guards trans hazard.
static __device__ __forceinline__ float ex2(float x) {
  float r;
  asm volatile("v_exp_f32 %0, %1\n\ts_nop 0" : "=v"(r) : "v"(x));
  return r;
}
static __device__ __forceinline__ u32 pkr(float a, float b) {
  union { h16x2 h; u32 u; } c;
  c.h = __builtin_amdgcn_cvt_pkrtz(a, b);
  return c.u;
}
#define MFMA16(a, b, c) __builtin_amdgcn_mfma_f32_16x16x32_f16(a, b, c, 0, 0, 0)
#define MFMA32(a, b, c) __builtin_amdgcn_mfma_f32_32x32x16_f16(a, b, c, 0, 0, 0)

// ---------------- prep: mask detect+convert, bias table (pre-scaled by log2e) ----------------
__global__ void k_prep(const void* msk, const float* __restrict__ rel,
                       float* __restrict__ biasT, unsigned char* __restrict__ m8) {
  __shared__ int o1s, o2s;
  const int t = threadIdx.x;
  if (t == 0) { o1s = 0; o2s = 0; }
  __syncthreads();
  const unsigned char* raw = (const unsigned char*)msk;
  int o1 = 0, o2 = 0;
  for (int i = t; i < BB * LKK; i += 256) {
    unsigned char vv = raw[i];
    if ((i & 3) && vv) o1 = 1;
    if (((i & 3) == 2) && vv == 0x80u) o2 = 1;
  }
  if (o1) atomicOr(&o1s, 1);
  if (o2) atomicOr(&o2s, 1);
  __syncthreads();
  const int f = o1s ? (o2s ? 2 : 1) : 0;  // 0=int32, 1=bool, 2=f32
  for (int i = t; i < BB * LKK; i += 256) {
    unsigned char v;
    if (f == 0)      v = (((const int*)msk)[i] != 0);
    else if (f == 1) v = (((const unsigned char*)msk)[i] != 0);
    else             v = (((const float*)msk)[i] != 0.0f);
    m8[i] = v;
  }
  for (int n = t; n < 2048; n += 256) {
    int bucket;
    if (n < 16) bucket = n;
    else {
      float tt = logf((float)n / 16.0f + 1e-9f);  // exact jax op order
      tt = tt / 2.0794415416798357f;
      tt = tt * 16.0f;
      bucket = 16 + (int)tt;
      if (bucket > 31) bucket = 31;
    }
    for (int h = 0; h < NHEADS; ++h)
      biasT[h * 2048 + n] = rel[bucket * NHEADS + h] * LOG2E;
  }
}

// ---------------- one merged fp32->fp16 convert for q,k,v,Wq,Wk,Wv,Wo ----------------
__global__ void k_cvt_all(const float* q, const float* k, const float* v,
                          const float* Wq, const float* Wk, const float* Wv, const float* Wo,
                          f16* Xq, f16* Xk, f16* Xv, f16* W16) {
  int i = blockIdx.x * 256 + threadIdx.x;  // 4194304 float4 units total
  const float* s; f16* d; int off;
  if (i < 3145728) {
    int which = i >> 20; off = i & 1048575;
    s = which == 0 ? q : (which == 1 ? k : v);
    d = which == 0 ? Xq : (which == 1 ? Xk : Xv);
  } else {
    int j = i - 3145728; int which = j >> 18; off = j & 262143;
    s = which == 0 ? Wq : (which == 1 ? Wk : (which == 2 ? Wv : Wo));
    d = W16 + which * 1048576;
  }
  float4 x = ((const float4*)s)[off];
  f16x4 o; o[0] = (f16)x.x; o[1] = (f16)x.y; o[2] = (f16)x.z; o[3] = (f16)x.w;
  ((f16x4*)d)[off] = o;
}

// ---------------- GEMM core: C = A[4096,1024] * B[1024,1024]^T ----------------
template <int EPI>
static __device__ __forceinline__ void gemm_core(const f16* __restrict__ A,
                                                 const f16* __restrict__ Bm,
                                                 void* __restrict__ C) {
  __shared__ __align__(16) f16 sA[128 * 32];
  __shared__ __align__(16) f16 sB[128 * 32];
  const int t = threadIdx.x;
  const int w = t >> 6, lane = t & 63;
  const int lg = lane >> 4, lc = lane & 15;
  const int wr = w >> 1, wc = w & 1;
  const long row0 = (long)blockIdx.x * 128;
  const long col0 = (long)blockIdx.y * 128;
  f32x4 acc[4][4] = {};

  for (int kk = 0; kk < 1024; kk += 32) {
#pragma unroll
    for (int it = 0; it < 2; ++it) {
      int ch = t + it * 256;
      int r = ch >> 2, kg = ch & 3;
      gload16(A + (row0 + r) * 1024 + kk + kg * 8, (char*)sA + ch * 16);
      gload16(Bm + (col0 + r) * 1024 + kk + kg * 8, (char*)sB + ch * 16);
    }
    __syncthreads();
    f16x8 af[4], bf[4];
#pragma unroll
    for (int i = 0; i < 4; ++i)
      af[i] = *(const f16x8*)&sA[(wr * 64 + i * 16 + lc) * 32 + lg * 8];
#pragma unroll
    for (int j = 0; j < 4; ++j)
      bf[j] = *(const f16x8*)&sB[(wc * 64 + j * 16 + lc) * 32 + lg * 8];
#pragma unroll
    for (int i = 0; i < 4; ++i)
#pragma unroll
      for (int j = 0; j < 4; ++j)
        acc[i][j] = MFMA16(af[i], bf[j], acc[i][j]);
    __syncthreads();
  }
#pragma unroll
  for (int i = 0; i < 4; ++i)
#pragma unroll
    for (int j = 0; j < 4; ++j)
#pragma unroll
      for (int r = 0; r < 4; ++r) {
        long row = row0 + wr * 64 + i * 16 + lg * 4 + r;
        long col = col0 + wc * 64 + j * 16 + lc;
        float v = acc[i][j][r];
        if (EPI == 0) {  // scatter into [B,H,L,64] f16
          long b = row >> 11, l = row & 2047;
          long h = col >> 6, d = col & 63;
          ((f16*)C)[(((b * NHEADS + h) * LQ) + l) * DHEAD + d] = (f16)v;
        } else {
          ((float*)C)[row * 1024 + col] = v;
        }
      }
}

__global__ void __launch_bounds__(256, 2)
k_gemm_qkv(const f16* __restrict__ Xq, const f16* __restrict__ Xk, const f16* __restrict__ Xv,
           const f16* __restrict__ W16, f16* __restrict__ QHp, f16* __restrict__ KHp,
           f16* __restrict__ VHp, int zoff) {
  const int z = blockIdx.z + zoff;
  const f16* A = z == 0 ? Xq : (z == 1 ? Xk : Xv);
  const f16* Bm = W16 + (size_t)z * 1048576;
  f16* C = z == 0 ? QHp : (z == 1 ? KHp : VHp);
  gemm_core<0>(A, Bm, C);
}

__global__ void __launch_bounds__(256, 2)
k_gemm_o(const f16* __restrict__ A, const f16* __restrict__ Bm, float* __restrict__ C) {
  gemm_core<1>(A, Bm, C);
}

// ---------------- flash attention: swapped-QK^T, 32x32 MFMA, in-register softmax ----------------
// 4 warps/block, 32 q-rows/warp (128/block). Grid 512 = 16 qchunks x 32 (b,h), XCD-clustered.
__global__ void __launch_bounds__(256, 2)
k_attn(const f16* __restrict__ QH, const f16* __restrict__ KH, const f16* __restrict__ VH,
       const float* __restrict__ BIASg, const unsigned char* __restrict__ M8,
       f16* __restrict__ O16) {
  __shared__ __align__(16) f16 sK[2][64 * 64];   // K tiles, XOR-swizzled rows
  __shared__ __align__(16) f16 sVT[2][64 * 64];  // V^T tiles, XOR-swizzled rows
  __shared__ __align__(16) float sBias[4104];    // bias*log2e, padded for n<0
  __shared__ __align__(16) float sPen[2048];     // mask penalty (log2 domain)

  const int L = blockIdx.x;
  const int bh = (L & 7) * 4 + ((L >> 3) & 3);   // same-bh blocks -> same XCD (L%8 fixed)
  const int qc = L >> 5;
  const int b = bh >> 4, h = bh & 15;
  const int t = threadIdx.x, w = t >> 6, lane = t & 63;
  const int lq = lane & 31;                      // this lane's q (and d-row for PV)
  const int hi = lane >> 5;
  const int q0w = qc * 128 + w * 32;
  const size_t base = (size_t)bh * LKK * DHEAD;

  for (int i = t; i < 4104; i += 256) {
    int n = i - 2052; n = n < 0 ? 0 : (n > 2047 ? 2047 : n);
    sBias[i] = BIASg[h * 2048 + n];
  }
  for (int i = t; i < 2048; i += 256)
    sPen[i] = M8[b * LKK + i] ? 0.0f : -3.0e9f;

  // Q B-frags straight from global: lane holds Q[q=lq][d = s*16 + hi*8 .. +8]
  f16x8 qb[4];
  const f16* qrow = QH + base + (size_t)(q0w + lq) * DHEAD;
#pragma unroll
  for (int s = 0; s < 4; ++s)
    qb[s] = *(const f16x8*)(qrow + s * 16 + hi * 8);

  auto STAGE = [&](int kt, int buf) {
#pragma unroll
    for (int it = 0; it < 2; ++it) {  // K: pre-swizzled global src -> linear LDS dest
      int ch = t + it * 256;
      int r = ch >> 3, g = ch & 7;
      gload16(KH + base + (size_t)(kt * 64 + r) * DHEAD + (g ^ (r & 7)) * 8,
              (char*)&sK[buf][0] + ch * 16);
    }
#pragma unroll
    for (int it = 0; it < 2; ++it) {  // V: register-transpose into swizzled V^T
      int ch = t + it * 256;
      int kr = ch & 63, dg = ch >> 6;
      uint4 vv = *(const uint4*)(VH + base + (size_t)(kt * 64 + kr) * DHEAD + dg * 8);
      const f16* pv = (const f16*)&vv;
#pragma unroll
      for (int e = 0; e < 8; ++e) {
        int d = dg * 8 + e;
        *(f16*)((char*)&sVT[buf][0] + ((d * 128 + kr * 2) ^ ((d & 7) << 4))) = pv[e];
      }
    }
  };

  float m_r = -1e30f, l_r = 0.0f;
  f32x16 oacc0 = {}, oacc1 = {};
  const float c1 = 0.125f * LOG2E;

  STAGE(0, 0);
  __syncthreads();

  for (int kt = 0; kt < 32; ++kt) {
    const int cur = kt & 1;
    if (kt < 31) STAGE(kt + 1, cur ^ 1);

    // S^T = K * Q^T : lane owns q-col lq; rows = k
    f32x16 sa0 = {}, sa1 = {};
#pragma unroll
    for (int s = 0; s < 4; ++s) {
      f16x8 k0 = *(const f16x8*)((const char*)&sK[cur][0] +
                   ((lq * 128 + s * 32 + hi * 16) ^ ((lq & 7) << 4)));
      f16x8 k1 = *(const f16x8*)((const char*)&sK[cur][0] +
                   (((32 + lq) * 128 + s * 32 + hi * 16) ^ ((lq & 7) << 4)));
      sa0 = MFMA32(k0, qb[s], sa0);
      sa1 = MFMA32(k1, qb[s], sa1);
    }

    float p_[32];
#pragma unroll
    for (int r = 0; r < 16; ++r) { p_[r] = sa0[r]; p_[16 + r] = sa1[r]; }

    // scale + bias + mask penalty (all log2-domain): k = kt*64 + tt*32 + j*8 + hi*4 + e
#pragma unroll
    for (int u = 0; u < 8; ++u) {
      int tt = u >> 2, j = u & 3;
      int kbase = kt * 64 + tt * 32 + j * 8 + hi * 4;
      f32x4 pen4 = *(const f32x4*)&sPen[kbase];
      int bidx0 = (q0w + lq) - kbase + 2052;
#pragma unroll
      for (int e = 0; e < 4; ++e) {
        float bp = sBias[bidx0 - e] + pen4[e];
        int r = tt * 16 + j * 4 + e;
        p_[r] = p_[r] * c1 + bp;
      }
    }

    // row max: in-register tree + cross-half exchange
    float tm[16];
#pragma unroll
    for (int r = 0; r < 16; ++r) tm[r] = fmaxf(p_[2 * r], p_[2 * r + 1]);
#pragma unroll
    for (int s = 8; s > 0; s >>= 1)
#pragma unroll
      for (int r = 0; r < s; ++r) tm[r] = fmaxf(tm[r], tm[r + s]);
    float mx = fmaxf(tm[0], __shfl_xor(tm[0], 32));

    // defer-max rescale (THR=8 in log2 domain)
    if (__any(mx > m_r + 8.0f)) {
      float mnew = fmaxf(m_r, mx);
      float al = ex2(m_r - mnew);
      m_r = mnew; l_r *= al;
#pragma unroll
      for (int r = 0; r < 16; ++r) { oacc0[r] *= al; oacc1[r] *= al; }
    }

#pragma unroll
    for (int r = 0; r < 32; ++r) p_[r] = ex2(p_[r] - m_r);

    float ts[16];
#pragma unroll
    for (int r = 0; r < 16; ++r) ts[r] = p_[2 * r] + p_[2 * r + 1];
#pragma unroll
    for (int s = 8; s > 0; s >>= 1)
#pragma unroll
      for (int r = 0; r < s; ++r) ts[r] += ts[r + s];
    l_r += ts[0] + __shfl_xor(ts[0], 32);

    // pack P -> f16 B-frags via cvt_pk + permlane32_swap (T12)
    f16x8 pf[4];
#pragma unroll
    for (int sl = 0; sl < 4; ++sl) {
      int tt = sl >> 1, sp = sl & 1;
      int bA = tt * 16 + (2 * sp) * 4, bB = tt * 16 + (2 * sp + 1) * 4;
      u32 A0 = pkr(p_[bA], p_[bA + 1]);
      u32 A1 = pkr(p_[bA + 2], p_[bA + 3]);
      u32 B0 = pkr(p_[bB], p_[bB + 1]);
      u32 B1 = pkr(p_[bB + 2], p_[bB + 3]);
      asm volatile("v_permlane32_swap_b32 %0, %1" : "+v"(A0), "+v"(B0));
      asm volatile("v_permlane32_swap_b32 %0, %1" : "+v"(A1), "+v"(B1));
      union { u32 u[4]; f16x8 v; } c;
      c.u[0] = A0; c.u[1] = A1; c.u[2] = B0; c.u[3] = B1;
      pf[sl] = c.v;
    }

    // O^T += V^T * P : lane owns q-col lq; rows = d
#pragma unroll
    for (int sl = 0; sl < 4; ++sl) {
      int K0 = sl * 16;
      f16x8 v0 = *(const f16x8*)((const char*)&sVT[cur][0] +
                   ((lq * 128 + K0 * 2 + hi * 16) ^ ((lq & 7) << 4)));
      f16x8 v1 = *(const f16x8*)((const char*)&sVT[cur][0] +
                   (((32 + lq) * 128 + K0 * 2 + hi * 16) ^ ((lq & 7) << 4)));
      oacc0 = MFMA32(v0, pf[sl], oacc0);
      oacc1 = MFMA32(v1, pf[sl], oacc1);
    }
    __syncthreads();
  }

  // normalize + store (lane owns q-row; d from reg pattern)
  const float rinv = 1.0f / l_r;
  const size_t orow = ((size_t)b * LQ + (q0w + lq)) * D_MODEL + h * DHEAD;
#pragma unroll
  for (int dh = 0; dh < 2; ++dh)
#pragma unroll
    for (int j = 0; j < 4; ++j) {
      int d0 = dh * 32 + j * 8 + hi * 4;
      f16x4 ov;
#pragma unroll
      for (int e = 0; e < 4; ++e) {
        float x = (dh ? oacc1[j * 4 + e] : oacc0[j * 4 + e]) * rinv;
        ov[e] = (f16)x;
      }
      *(f16x4*)(O16 + orow + d0) = ov;
    }
}

// ---------------- launch ----------------
extern "C" void kernel_launch(void* const* d_in, const int* in_sizes, int n_in,
                              void* d_out, int out_size, void* d_ws, size_t ws_size,
                              hipStream_t stream) {
  (void)in_sizes; (void)n_in; (void)out_size;
  const float* q   = (const float*)d_in[0];
  const float* k   = (const float*)d_in[1];
  const float* v   = (const float*)d_in[2];
  const void*  msk = d_in[3];
  const float* Wq  = (const float*)d_in[4];
  const float* Wk  = (const float*)d_in[5];
  const float* Wv  = (const float*)d_in[6];
  const float* Wo  = (const float*)d_in[7];
  const float* rel = (const float*)d_in[8];

  char* ws = (char*)d_ws;
  const size_t SL = (size_t)8 << 20;
  const bool bigA = ws_size >= 8 * SL;  // concurrent-QKV layout needs 7 slabs + misc

  f16 *Xq, *Xk, *Xv, *QHp, *KHp, *VHp, *O16, *W16; char* misc;
  if (bigA) {
    Xq = (f16*)(ws + 0 * SL); Xk = (f16*)(ws + 1 * SL); Xv = (f16*)(ws + 2 * SL);
    QHp = (f16*)(ws + 3 * SL); KHp = (f16*)(ws + 4 * SL); VHp = (f16*)(ws + 5 * SL);
    W16 = (f16*)(ws + 6 * SL); O16 = (f16*)(ws + 2 * SL);  // Xv consumed before attn
    misc = ws + 7 * SL;
  } else {  // sequential layout (round-1 style reuse)
    Xq = (f16*)(ws + 0 * SL); Xk = (f16*)(ws + 1 * SL); Xv = (f16*)(ws + 2 * SL);
    QHp = (f16*)(ws + 3 * SL); KHp = (f16*)(ws + 0 * SL); VHp = (f16*)(ws + 1 * SL);
    W16 = (f16*)(ws + 4 * SL); O16 = (f16*)(ws + 2 * SL);
    misc = ws + 5 * SL;
  }
  float* BIAS = (float*)misc;                       // 16*2048 f32 = 128KB
  unsigned char* M8 = (unsigned char*)(misc + (192 << 10));

  k_prep<<<1, 256, 0, stream>>>(msk, rel, BIAS, M8);
  k_cvt_all<<<16384, 256, 0, stream>>>(q, k, v, Wq, Wk, Wv, Wo, Xq, Xk, Xv, W16);

  if (bigA) {
    k_gemm_qkv<<<dim3(32, 8, 3), 256, 0, stream>>>(Xq, Xk, Xv, W16, QHp, KHp, VHp, 0);
  } else {
    for (int z = 0; z < 3; ++z)
      k_gemm_qkv<<<dim3(32, 8, 1), 256, 0, stream>>>(Xq, Xk, Xv, W16, QHp, KHp, VHp, z);
  }
  k_attn<<<512, 256, 0, stream>>>(QHp, KHp, VHp, BIAS, M8, O16);
  k_gemm_o<<<dim3(32, 8), 256, 0, stream>>>(O16, W16 + 3 * 1048576, (float*)d_out);
}

// Round 4
// 155.109 us; speedup vs baseline: 1.7821x; 1.0637x over previous
//
#include <hip/hip_runtime.h>
#include <math.h>

typedef _Float16 f16;
typedef __fp16 h16x2 __attribute__((ext_vector_type(2)));
typedef _Float16 f16x4 __attribute__((ext_vector_type(4)));
typedef _Float16 f16x8 __attribute__((ext_vector_type(8)));
typedef float f32x4 __attribute__((ext_vector_type(4)));
typedef float f32x16 __attribute__((ext_vector_type(16)));
typedef unsigned int u32;

#define D_MODEL 1024
#define NHEADS 16
#define DHEAD 64
#define LQ 2048
#define LKK 2048
#define BB 2
#define LOG2E 1.4426950408889634f

static __device__ __forceinline__ void gload16(const void* g, void* l) {
  __builtin_amdgcn_global_load_lds(
      (const __attribute__((address_space(1))) u32*)g,
      (__attribute__((address_space(3))) u32*)l, 16, 0, 0);
}
static __device__ __forceinline__ float ex2(float x) {
  float r;
  asm volatile("v_exp_f32 %0, %1\n\ts_nop 0" : "=v"(r) : "v"(x));
  return r;
}
static __device__ __forceinline__ u32 pkr(float a, float b) {
  union { h16x2 h; u32 u; } c;
  c.h = __builtin_amdgcn_cvt_pkrtz(a, b);
  return c.u;
}
static __device__ __forceinline__ float fmax3(float a, float b, float c) {
  return fmaxf(fmaxf(a, b), c);  // clang fuses to v_max3_f32
}
#define MFMA16(a, b, c) __builtin_amdgcn_mfma_f32_16x16x32_f16(a, b, c, 0, 0, 0)
#define MFMA32(a, b, c) __builtin_amdgcn_mfma_f32_32x32x16_f16(a, b, c, 0, 0, 0)

// ---------------- prep: mask detect+convert, bias table (pre-scaled by log2e) ----------------
__global__ void k_prep(const void* msk, const float* __restrict__ rel,
                       float* __restrict__ biasT, unsigned char* __restrict__ m8) {
  __shared__ int o1s, o2s;
  const int t = threadIdx.x;
  if (t == 0) { o1s = 0; o2s = 0; }
  __syncthreads();
  const unsigned char* raw = (const unsigned char*)msk;
  int o1 = 0, o2 = 0;
  for (int i = t; i < BB * LKK; i += 256) {
    unsigned char vv = raw[i];
    if ((i & 3) && vv) o1 = 1;
    if (((i & 3) == 2) && vv == 0x80u) o2 = 1;
  }
  if (o1) atomicOr(&o1s, 1);
  if (o2) atomicOr(&o2s, 1);
  __syncthreads();
  const int f = o1s ? (o2s ? 2 : 1) : 0;  // 0=int32, 1=bool, 2=f32
  for (int i = t; i < BB * LKK; i += 256) {
    unsigned char v;
    if (f == 0)      v = (((const int*)msk)[i] != 0);
    else if (f == 1) v = (((const unsigned char*)msk)[i] != 0);
    else             v = (((const float*)msk)[i] != 0.0f);
    m8[i] = v;
  }
  for (int n = t; n < 2048; n += 256) {
    int bucket;
    if (n < 16) bucket = n;
    else {
      float tt = logf((float)n / 16.0f + 1e-9f);  // exact jax op order
      tt = tt / 2.0794415416798357f;
      tt = tt * 16.0f;
      bucket = 16 + (int)tt;
      if (bucket > 31) bucket = 31;
    }
    for (int h = 0; h < NHEADS; ++h)
      biasT[h * 2048 + n] = rel[bucket * NHEADS + h] * LOG2E;
  }
}

// ---------------- one merged fp32->fp16 convert for q,k,v,Wq,Wk,Wv,Wo ----------------
__global__ void k_cvt_all(const float* q, const float* k, const float* v,
                          const float* Wq, const float* Wk, const float* Wv, const float* Wo,
                          f16* Xq, f16* Xk, f16* Xv, f16* W16) {
  int i = blockIdx.x * 256 + threadIdx.x;  // 4194304 float4 units total
  const float* s; f16* d; int off;
  if (i < 3145728) {
    int which = i >> 20; off = i & 1048575;
    s = which == 0 ? q : (which == 1 ? k : v);
    d = which == 0 ? Xq : (which == 1 ? Xk : Xv);
  } else {
    int j = i - 3145728; int which = j >> 18; off = j & 262143;
    s = which == 0 ? Wq : (which == 1 ? Wk : (which == 2 ? Wv : Wo));
    d = W16 + which * 1048576;
  }
  float4 x = ((const float4*)s)[off];
  f16x4 o; o[0] = (f16)x.x; o[1] = (f16)x.y; o[2] = (f16)x.z; o[3] = (f16)x.w;
  ((f16x4*)d)[off] = o;
}

// ---------------- GEMM core: C = A[4096,1024] * B[1024,1024]^T ----------------
// EPI 0: f16 scatter into [B,H,L,64].  EPI 1: fp32 row-major.  EPI 2: f16 V^T [B,H,64,L].
template <int EPI>
static __device__ __forceinline__ void gemm_core(const f16* __restrict__ A,
                                                 const f16* __restrict__ Bm,
                                                 void* __restrict__ C) {
  __shared__ __align__(16) f16 sA[128 * 32];
  __shared__ __align__(16) f16 sB[128 * 32];
  const int t = threadIdx.x;
  const int w = t >> 6, lane = t & 63;
  const int lg = lane >> 4, lc = lane & 15;
  const int wr = w >> 1, wc = w & 1;
  const long row0 = (long)blockIdx.x * 128;
  const long col0 = (long)blockIdx.y * 128;
  f32x4 acc[4][4] = {};

  for (int kk = 0; kk < 1024; kk += 32) {
#pragma unroll
    for (int it = 0; it < 2; ++it) {
      int ch = t + it * 256;
      int r = ch >> 2, kg = ch & 3;
      gload16(A + (row0 + r) * 1024 + kk + kg * 8, (char*)sA + ch * 16);
      gload16(Bm + (col0 + r) * 1024 + kk + kg * 8, (char*)sB + ch * 16);
    }
    __syncthreads();
    f16x8 af[4], bf[4];
#pragma unroll
    for (int i = 0; i < 4; ++i)
      af[i] = *(const f16x8*)&sA[(wr * 64 + i * 16 + lc) * 32 + lg * 8];
#pragma unroll
    for (int j = 0; j < 4; ++j)
      bf[j] = *(const f16x8*)&sB[(wc * 64 + j * 16 + lc) * 32 + lg * 8];
#pragma unroll
    for (int i = 0; i < 4; ++i)
#pragma unroll
      for (int j = 0; j < 4; ++j)
        acc[i][j] = MFMA16(af[i], bf[j], acc[i][j]);
    __syncthreads();
  }
#pragma unroll
  for (int i = 0; i < 4; ++i)
#pragma unroll
    for (int j = 0; j < 4; ++j) {
      const long rowb = row0 + wr * 64 + i * 16 + lg * 4;  // 4 consecutive rows (r)
      const long col = col0 + wc * 64 + j * 16 + lc;
      if (EPI == 2) {  // V^T: [b,h,d,l] with f16x4 over l (=r)
        long b = rowb >> 11, l0 = rowb & 2047;
        long h = col >> 6, d = col & 63;
        f16x4 ov;
#pragma unroll
        for (int r = 0; r < 4; ++r) ov[r] = (f16)acc[i][j][r];
        *(f16x4*)((f16*)C + (((b * NHEADS + h) * DHEAD + d) * (long)LKK + l0)) = ov;
      } else {
#pragma unroll
        for (int r = 0; r < 4; ++r) {
          long row = rowb + r;
          float v = acc[i][j][r];
          if (EPI == 0) {
            long b = row >> 11, l = row & 2047;
            long h = col >> 6, d = col & 63;
            ((f16*)C)[(((b * NHEADS + h) * LQ) + l) * DHEAD + d] = (f16)v;
          } else {
            ((float*)C)[row * 1024 + col] = v;
          }
        }
      }
    }
}

__global__ void __launch_bounds__(256, 3)
k_gemm_qkv(const f16* __restrict__ Xq, const f16* __restrict__ Xk, const f16* __restrict__ Xv,
           const f16* __restrict__ W16, f16* __restrict__ QHp, f16* __restrict__ KHp,
           f16* __restrict__ VTp, int zoff) {
  const int z = blockIdx.z + zoff;
  if (z == 2) {
    gemm_core<2>(Xv, W16 + 2 * 1048576, VTp);
  } else {
    const f16* A = z == 0 ? Xq : Xk;
    const f16* Bm = W16 + (size_t)z * 1048576;
    f16* C = z == 0 ? QHp : KHp;
    gemm_core<0>(A, Bm, C);
  }
}

__global__ void __launch_bounds__(256, 2)
k_gemm_o(const f16* __restrict__ A, const f16* __restrict__ Bm, float* __restrict__ C) {
  gemm_core<1>(A, Bm, C);
}

// ---------------- flash attention: swapped-QK^T, 32x32 MFMA, in-register softmax ----------------
// 4 warps/block, 32 q-rows/warp (128/block). Grid 512 = 16 qchunks x 32 (b,h), XCD-clustered.
__global__ void __launch_bounds__(256, 2)
k_attn(const f16* __restrict__ QH, const f16* __restrict__ KH, const f16* __restrict__ VT,
       const float* __restrict__ BIASg, const unsigned char* __restrict__ M8,
       f16* __restrict__ O16) {
  __shared__ __align__(16) f16 sK[2][64 * 64];   // K tiles, XOR-swizzled rows
  __shared__ __align__(16) f16 sVT[2][64 * 64];  // V^T tiles, XOR-swizzled rows
  __shared__ __align__(16) float sBias[4104];    // bias*log2e, padded for n<0
  __shared__ __align__(16) float sPen[2048];     // mask penalty (log2 domain)

  const int L = blockIdx.x;
  const int bh = (L & 7) * 4 + ((L >> 3) & 3);   // same-bh blocks -> same XCD (L%8 fixed)
  const int qc = L >> 5;
  const int b = bh >> 4, h = bh & 15;
  const int t = threadIdx.x, w = t >> 6, lane = t & 63;
  const int lq = lane & 31;                      // this lane's q (and d-row for PV)
  const int hi = lane >> 5;
  const int q0w = qc * 128 + w * 32;
  const size_t base = (size_t)bh * LKK * DHEAD;  // K: [bh][k][d];  VT: [bh][d][k] (same bytes)

  for (int i = t; i < 4104; i += 256) {
    int n = i - 2052; n = n < 0 ? 0 : (n > 2047 ? 2047 : n);
    sBias[i] = BIASg[h * 2048 + n];
  }
  for (int i = t; i < 2048; i += 256)
    sPen[i] = M8[b * LKK + i] ? 0.0f : -3.0e9f;

  // Q B-frags straight from global: lane holds Q[q=lq][d = s*16 + hi*8 .. +8]
  f16x8 qb[4];
  const f16* qrow = QH + base + (size_t)(q0w + lq) * DHEAD;
#pragma unroll
  for (int s = 0; s < 4; ++s)
    qb[s] = *(const f16x8*)(qrow + s * 16 + hi * 8);

  // per-thread staging geometry (identical for K rows and V^T rows)
  const int ch0 = t, ch1 = t + 256;
  const int r0 = ch0 >> 3, g0 = ((ch0 & 7) ^ (r0 & 7)) * 8;
  const int r1 = ch1 >> 3, g1 = ((ch1 & 7) ^ (r1 & 7)) * 8;
  const f16* Kb = KH + base;
  const f16* Vb = VT + base;

  auto STAGE = [&](int kt, int buf) {
    const int k0 = kt * 64;
    gload16(Kb + (size_t)(k0 + r0) * DHEAD + g0, (char*)&sK[buf][0] + ch0 * 16);
    gload16(Kb + (size_t)(k0 + r1) * DHEAD + g1, (char*)&sK[buf][0] + ch1 * 16);
    gload16(Vb + (size_t)r0 * LKK + k0 + g0, (char*)&sVT[buf][0] + ch0 * 16);
    gload16(Vb + (size_t)r1 * LKK + k0 + g1, (char*)&sVT[buf][0] + ch1 * 16);
  };

  float m_r = -1e30f;
  f32x16 oacc0 = {}, oacc1 = {}, oaccL = {};
  const float c1 = 0.125f * LOG2E;
  f16x8 ones;
#pragma unroll
  for (int e = 0; e < 8; ++e) ones[e] = (f16)1.0f;

  STAGE(0, 0);
  __syncthreads();

  for (int kt = 0; kt < 32; ++kt) {
    const int cur = kt & 1;
    if (kt < 31) STAGE(kt + 1, cur ^ 1);

    // S^T = K * Q^T : lane owns q-col lq; rows = k
    f32x16 sa0 = {}, sa1 = {};
#pragma unroll
    for (int s = 0; s < 4; ++s) {
      f16x8 k0 = *(const f16x8*)((const char*)&sK[cur][0] +
                   ((lq * 128 + s * 32 + hi * 16) ^ ((lq & 7) << 4)));
      f16x8 k1 = *(const f16x8*)((const char*)&sK[cur][0] +
                   (((32 + lq) * 128 + s * 32 + hi * 16) ^ ((lq & 7) << 4)));
      sa0 = MFMA32(k0, qb[s], sa0);
      sa1 = MFMA32(k1, qb[s], sa1);
    }

    float p_[32];
#pragma unroll
    for (int r = 0; r < 16; ++r) { p_[r] = sa0[r]; p_[16 + r] = sa1[r]; }

    // scale + bias + mask penalty (all log2-domain): k = kt*64 + tt*32 + j*8 + hi*4 + e
#pragma unroll
    for (int u = 0; u < 8; ++u) {
      int tt = u >> 2, j = u & 3;
      int kbase = kt * 64 + tt * 32 + j * 8 + hi * 4;
      f32x4 pen4 = *(const f32x4*)&sPen[kbase];
      int bidx0 = (q0w + lq) - kbase + 2052;
#pragma unroll
      for (int e = 0; e < 4; ++e) {
        float bp = sBias[bidx0 - e] + pen4[e];
        int r = tt * 16 + j * 4 + e;
        p_[r] = p_[r] * c1 + bp;
      }
    }

    // row max: max3 triples + cross-half exchange
    float mm[11];
#pragma unroll
    for (int r = 0; r < 10; ++r) mm[r] = fmax3(p_[3 * r], p_[3 * r + 1], p_[3 * r + 2]);
    mm[10] = fmaxf(p_[30], p_[31]);
    float a0 = fmax3(mm[0], mm[1], mm[2]);
    float a1 = fmax3(mm[3], mm[4], mm[5]);
    float a2 = fmax3(mm[6], mm[7], mm[8]);
    float a3 = fmax3(mm[9], mm[10], a0);
    float mx = fmax3(a1, a2, a3);
    mx = fmaxf(mx, __shfl_xor(mx, 32));

    // defer-max rescale (THR=8 in log2 domain)
    if (__any(mx > m_r + 8.0f)) {
      float mnew = fmaxf(m_r, mx);
      float al = ex2(m_r - mnew);
      m_r = mnew;
#pragma unroll
      for (int r = 0; r < 16; ++r) { oacc0[r] *= al; oacc1[r] *= al; oaccL[r] *= al; }
    }

#pragma unroll
    for (int r = 0; r < 32; ++r) p_[r] = ex2(p_[r] - m_r);

    // pack P -> f16 B-frags via cvt_pk + permlane32_swap (T12)
    f16x8 pf[4];
#pragma unroll
    for (int sl = 0; sl < 4; ++sl) {
      int tt = sl >> 1, sp = sl & 1;
      int bA = tt * 16 + (2 * sp) * 4, bB = tt * 16 + (2 * sp + 1) * 4;
      u32 A0 = pkr(p_[bA], p_[bA + 1]);
      u32 A1 = pkr(p_[bA + 2], p_[bA + 3]);
      u32 B0 = pkr(p_[bB], p_[bB + 1]);
      u32 B1 = pkr(p_[bB + 2], p_[bB + 3]);
      asm volatile("v_permlane32_swap_b32 %0, %1" : "+v"(A0), "+v"(B0));
      asm volatile("v_permlane32_swap_b32 %0, %1" : "+v"(A1), "+v"(B1));
      union { u32 u[4]; f16x8 v; } c;
      c.u[0] = A0; c.u[1] = A1; c.u[2] = B0; c.u[3] = B1;
      pf[sl] = c.v;
    }

    // O^T += V^T * P (rows = d); l-row via ones-MFMA on the idle matrix pipe
#pragma unroll
    for (int sl = 0; sl < 4; ++sl) {
      int K0 = sl * 16;
      f16x8 v0 = *(const f16x8*)((const char*)&sVT[cur][0] +
                   ((lq * 128 + K0 * 2 + hi * 16) ^ ((lq & 7) << 4)));
      f16x8 v1 = *(const f16x8*)((const char*)&sVT[cur][0] +
                   (((32 + lq) * 128 + K0 * 2 + hi * 16) ^ ((lq & 7) << 4)));
      oacc0 = MFMA32(v0, pf[sl], oacc0);
      oacc1 = MFMA32(v1, pf[sl], oacc1);
      oaccL = MFMA32(ones, pf[sl], oaccL);
    }
    __syncthreads();
  }

  // normalize + store (lane owns q-row; d from reg pattern); l = any row of oaccL
  const float rinv = 1.0f / oaccL[0];
  const size_t orow = ((size_t)b * LQ + (q0w + lq)) * D_MODEL + h * DHEAD;
#pragma unroll
  for (int dh = 0; dh < 2; ++dh)
#pragma unroll
    for (int j = 0; j < 4; ++j) {
      int d0 = dh * 32 + j * 8 + hi * 4;
      f16x4 ov;
#pragma unroll
      for (int e = 0; e < 4; ++e) {
        float x = (dh ? oacc1[j * 4 + e] : oacc0[j * 4 + e]) * rinv;
        ov[e] = (f16)x;
      }
      *(f16x4*)(O16 + orow + d0) = ov;
    }
}

// ---------------- launch ----------------
extern "C" void kernel_launch(void* const* d_in, const int* in_sizes, int n_in,
                              void* d_out, int out_size, void* d_ws, size_t ws_size,
                              hipStream_t stream) {
  (void)in_sizes; (void)n_in; (void)out_size;
  const float* q   = (const float*)d_in[0];
  const float* k   = (const float*)d_in[1];
  const float* v   = (const float*)d_in[2];
  const void*  msk = d_in[3];
  const float* Wq  = (const float*)d_in[4];
  const float* Wk  = (const float*)d_in[5];
  const float* Wv  = (const float*)d_in[6];
  const float* Wo  = (const float*)d_in[7];
  const float* rel = (const float*)d_in[8];

  char* ws = (char*)d_ws;
  const size_t SL = (size_t)8 << 20;
  const bool bigA = ws_size >= 8 * SL;

  f16 *Xq, *Xk, *Xv, *QHp, *KHp, *VTp, *O16, *W16; char* misc;
  if (bigA) {
    Xq = (f16*)(ws + 0 * SL); Xk = (f16*)(ws + 1 * SL); Xv = (f16*)(ws + 2 * SL);
    QHp = (f16*)(ws + 3 * SL); KHp = (f16*)(ws + 4 * SL); VTp = (f16*)(ws + 5 * SL);
    W16 = (f16*)(ws + 6 * SL); O16 = (f16*)(ws + 2 * SL);
    misc = ws + 7 * SL;
  } else {
    Xq = (f16*)(ws + 0 * SL); Xk = (f16*)(ws + 1 * SL); Xv = (f16*)(ws + 2 * SL);
    QHp = (f16*)(ws + 3 * SL); KHp = (f16*)(ws + 0 * SL); VTp = (f16*)(ws + 1 * SL);
    W16 = (f16*)(ws + 4 * SL); O16 = (f16*)(ws + 2 * SL);
    misc = ws + 5 * SL;
  }
  float* BIAS = (float*)misc;
  unsigned char* M8 = (unsigned char*)(misc + (192 << 10));

  k_prep<<<1, 256, 0, stream>>>(msk, rel, BIAS, M8);
  k_cvt_all<<<16384, 256, 0, stream>>>(q, k, v, Wq, Wk, Wv, Wo, Xq, Xk, Xv, W16);

  if (bigA) {
    k_gemm_qkv<<<dim3(32, 8, 3), 256, 0, stream>>>(Xq, Xk, Xv, W16, QHp, KHp, VTp, 0);
  } else {
    for (int z = 0; z < 3; ++z)
      k_gemm_qkv<<<dim3(32, 8, 1), 256, 0, stream>>>(Xq, Xk, Xv, W16, QHp, KHp, VTp, z);
  }
  k_attn<<<512, 256, 0, stream>>>(QHp, KHp, VTp, BIAS, M8, O16);
  k_gemm_o<<<dim3(32, 8), 256, 0, stream>>>(O16, W16 + 3 * 1048576, (float*)d_out);
}

// Round 5
// 152.229 us; speedup vs baseline: 1.8159x; 1.0189x over previous
//
#include <hip/hip_runtime.h>
#include <math.h>

typedef _Float16 f16;
typedef __fp16 h16x2 __attribute__((ext_vector_type(2)));
typedef _Float16 f16x4 __attribute__((ext_vector_type(4)));
typedef _Float16 f16x8 __attribute__((ext_vector_type(8)));
typedef float f32x4 __attribute__((ext_vector_type(4)));
typedef float f32x16 __attribute__((ext_vector_type(16)));
typedef unsigned int u32;

#define D_MODEL 1024
#define NHEADS 16
#define DHEAD 64
#define LQ 2048
#define LKK 2048
#define BB 2
#define LOG2E 1.4426950408889634f

static __device__ __forceinline__ void gload16(const void* g, void* l) {
  __builtin_amdgcn_global_load_lds(
      (const __attribute__((address_space(1))) u32*)g,
      (__attribute__((address_space(3))) u32*)l, 16, 0, 0);
}
static __device__ __forceinline__ float ex2(float x) {
  float r;
  asm volatile("v_exp_f32 %0, %1\n\ts_nop 0" : "=v"(r) : "v"(x));
  return r;
}
static __device__ __forceinline__ u32 pkr(float a, float b) {
  union { h16x2 h; u32 u; } c;
  c.h = __builtin_amdgcn_cvt_pkrtz(a, b);
  return c.u;
}
static __device__ __forceinline__ float fmax3(float a, float b, float c) {
  return fmaxf(fmaxf(a, b), c);  // clang fuses to v_max3_f32
}
#define MFMA16(a, b, c) __builtin_amdgcn_mfma_f32_16x16x32_f16(a, b, c, 0, 0, 0)
#define MFMA32(a, b, c) __builtin_amdgcn_mfma_f32_32x32x16_f16(a, b, c, 0, 0, 0)

// ---------------- prep: mask detect+convert, bias table (pre-scaled by log2e) ----------------
__global__ void k_prep(const void* msk, const float* __restrict__ rel,
                       float* __restrict__ biasT, unsigned char* __restrict__ m8) {
  __shared__ int o1s, o2s;
  const int t = threadIdx.x;
  if (t == 0) { o1s = 0; o2s = 0; }
  __syncthreads();
  const unsigned char* raw = (const unsigned char*)msk;
  int o1 = 0, o2 = 0;
  for (int i = t; i < BB * LKK; i += 256) {
    unsigned char vv = raw[i];
    if ((i & 3) && vv) o1 = 1;
    if (((i & 3) == 2) && vv == 0x80u) o2 = 1;
  }
  if (o1) atomicOr(&o1s, 1);
  if (o2) atomicOr(&o2s, 1);
  __syncthreads();
  const int f = o1s ? (o2s ? 2 : 1) : 0;  // 0=int32, 1=bool, 2=f32
  for (int i = t; i < BB * LKK; i += 256) {
    unsigned char v;
    if (f == 0)      v = (((const int*)msk)[i] != 0);
    else if (f == 1) v = (((const unsigned char*)msk)[i] != 0);
    else             v = (((const float*)msk)[i] != 0.0f);
    m8[i] = v;
  }
  for (int n = t; n < 2048; n += 256) {
    int bucket;
    if (n < 16) bucket = n;
    else {
      float tt = logf((float)n / 16.0f + 1e-9f);  // exact jax op order
      tt = tt / 2.0794415416798357f;
      tt = tt * 16.0f;
      bucket = 16 + (int)tt;
      if (bucket > 31) bucket = 31;
    }
    for (int h = 0; h < NHEADS; ++h)
      biasT[h * 2048 + n] = rel[bucket * NHEADS + h] * LOG2E;
  }
}

// ---------------- one merged fp32->fp16 convert for q,k,v,Wq,Wk,Wv,Wo ----------------
__global__ void k_cvt_all(const float* q, const float* k, const float* v,
                          const float* Wq, const float* Wk, const float* Wv, const float* Wo,
                          f16* Xq, f16* Xk, f16* Xv, f16* W16) {
  int i = blockIdx.x * 256 + threadIdx.x;  // 4194304 float4 units total
  const float* s; f16* d; int off;
  if (i < 3145728) {
    int which = i >> 20; off = i & 1048575;
    s = which == 0 ? q : (which == 1 ? k : v);
    d = which == 0 ? Xq : (which == 1 ? Xk : Xv);
  } else {
    int j = i - 3145728; int which = j >> 18; off = j & 262143;
    s = which == 0 ? Wq : (which == 1 ? Wk : (which == 2 ? Wv : Wo));
    d = W16 + which * 1048576;
  }
  float4 x = ((const float4*)s)[off];
  f16x4 o; o[0] = (f16)x.x; o[1] = (f16)x.y; o[2] = (f16)x.z; o[3] = (f16)x.w;
  ((f16x4*)d)[off] = o;
}

// ---------------- GEMM core: C = A[4096,1024] * B[1024,1024]^T, tile 128 x BN ----------------
// EPI 0: f16 scatter into [B,H,L,64].  EPI 1: fp32 row-major.  EPI 2: f16 V^T [B,H,64,L].
template <int EPI, int BN>
static __device__ __forceinline__ void gemm_core(const f16* __restrict__ A,
                                                 const f16* __restrict__ Bm,
                                                 void* __restrict__ C) {
  constexpr int JN = BN / 32;  // col frags per wave
  __shared__ __align__(16) f16 sA[128 * 32];
  __shared__ __align__(16) f16 sB[BN * 32];
  const int t = threadIdx.x;
  const int w = t >> 6, lane = t & 63;
  const int lg = lane >> 4, lc = lane & 15;
  const int wr = w >> 1, wc = w & 1;
  const long row0 = (long)blockIdx.x * 128;
  const long col0 = (long)blockIdx.y * BN;
  f32x4 acc[4][JN] = {};

  for (int kk = 0; kk < 1024; kk += 32) {
#pragma unroll
    for (int it = 0; it < 2; ++it) {
      int ch = t + it * 256;
      int r = ch >> 2, kg = ch & 3;
      gload16(A + (row0 + r) * 1024 + kk + kg * 8, (char*)sA + ch * 16);
    }
#pragma unroll
    for (int it = 0; it < BN / 64; ++it) {
      int ch = t + it * 256;
      int r = ch >> 2, kg = ch & 3;
      gload16(Bm + (col0 + r) * 1024 + kk + kg * 8, (char*)sB + ch * 16);
    }
    __syncthreads();
    f16x8 af[4], bf[JN];
#pragma unroll
    for (int i = 0; i < 4; ++i)
      af[i] = *(const f16x8*)&sA[(wr * 64 + i * 16 + lc) * 32 + lg * 8];
#pragma unroll
    for (int j = 0; j < JN; ++j)
      bf[j] = *(const f16x8*)&sB[(wc * (16 * JN) + j * 16 + lc) * 32 + lg * 8];
#pragma unroll
    for (int i = 0; i < 4; ++i)
#pragma unroll
      for (int j = 0; j < JN; ++j)
        acc[i][j] = MFMA16(af[i], bf[j], acc[i][j]);
    __syncthreads();
  }
#pragma unroll
  for (int i = 0; i < 4; ++i)
#pragma unroll
    for (int j = 0; j < JN; ++j) {
      const long rowb = row0 + wr * 64 + i * 16 + lg * 4;  // 4 consecutive rows (r)
      const long col = col0 + wc * (16 * JN) + j * 16 + lc;
      if (EPI == 2) {  // V^T: [b,h,d,l] with f16x4 over l (=r)
        long b = rowb >> 11, l0 = rowb & 2047;
        long h = col >> 6, d = col & 63;
        f16x4 ov;
#pragma unroll
        for (int r = 0; r < 4; ++r) ov[r] = (f16)acc[i][j][r];
        *(f16x4*)((f16*)C + (((b * NHEADS + h) * DHEAD + d) * (long)LKK + l0)) = ov;
      } else {
#pragma unroll
        for (int r = 0; r < 4; ++r) {
          long row = rowb + r;
          float v = acc[i][j][r];
          if (EPI == 0) {
            long b = row >> 11, l = row & 2047;
            long h = col >> 6, d = col & 63;
            ((f16*)C)[(((b * NHEADS + h) * LQ) + l) * DHEAD + d] = (f16)v;
          } else {
            ((float*)C)[row * 1024 + col] = v;
          }
        }
      }
    }
}

__global__ void __launch_bounds__(256, 3)
k_gemm_qkv(const f16* __restrict__ Xq, const f16* __restrict__ Xk, const f16* __restrict__ Xv,
           const f16* __restrict__ W16, f16* __restrict__ QHp, f16* __restrict__ KHp,
           f16* __restrict__ VTp, int zoff) {
  const int z = blockIdx.z + zoff;
  if (z == 2) {
    gemm_core<2, 128>(Xv, W16 + 2 * 1048576, VTp);
  } else {
    const f16* A = z == 0 ? Xq : Xk;
    const f16* Bm = W16 + (size_t)z * 1048576;
    f16* C = z == 0 ? QHp : KHp;
    gemm_core<0, 128>(A, Bm, C);
  }
}

// 128x64 tile -> grid (32,16) = 512 blocks = 2 blocks/CU (was 1 at 128x128)
__global__ void __launch_bounds__(256, 2)
k_gemm_o(const f16* __restrict__ A, const f16* __restrict__ Bm, float* __restrict__ C) {
  gemm_core<1, 64>(A, Bm, C);
}

// ---------------- flash attention: swapped-QK^T, 32x32 MFMA, software-pipelined ----------------
// 4 warps/block, 32 q-rows/warp. Grid 512 = 16 qchunks x 32 (b,h), XCD-clustered.
// Pipeline: QK(kt+1) issued BEFORE softmax/PV(kt) so QK MFMAs overlap softmax VALU.
// K prefetch distance 2, V distance 1 (2x2 LDS buffers, no overlap across barriers).
__global__ void __launch_bounds__(256, 2)
k_attn(const f16* __restrict__ QH, const f16* __restrict__ KH, const f16* __restrict__ VT,
       const float* __restrict__ BIASg, const unsigned char* __restrict__ M8,
       f16* __restrict__ O16) {
  __shared__ __align__(16) f16 sK[2][64 * 64];   // K tiles, XOR-swizzled rows
  __shared__ __align__(16) f16 sVT[2][64 * 64];  // V^T tiles, XOR-swizzled rows
  __shared__ __align__(16) float sBias[4104];    // bias*log2e, padded for n<0
  __shared__ __align__(16) float sPen[2048];     // mask penalty (log2 domain)

  const int L = blockIdx.x;
  const int bh = (L & 7) * 4 + ((L >> 3) & 3);   // same-bh blocks -> same XCD (L%8 fixed)
  const int qc = L >> 5;
  const int b = bh >> 4, h = bh & 15;
  const int t = threadIdx.x, w = t >> 6, lane = t & 63;
  const int lq = lane & 31;                      // this lane's q (and d-row for PV)
  const int hi = lane >> 5;
  const int q0w = qc * 128 + w * 32;
  const size_t base = (size_t)bh * LKK * DHEAD;

  for (int i = t; i < 4104; i += 256) {
    int n = i - 2052; n = n < 0 ? 0 : (n > 2047 ? 2047 : n);
    sBias[i] = BIASg[h * 2048 + n];
  }
  for (int i = t; i < 2048; i += 256)
    sPen[i] = M8[b * LKK + i] ? 0.0f : -3.0e9f;

  // Q B-frags straight from global: lane holds Q[q=lq][d = s*16 + hi*8 .. +8]
  f16x8 qb[4];
  const f16* qrow = QH + base + (size_t)(q0w + lq) * DHEAD;
#pragma unroll
  for (int s = 0; s < 4; ++s)
    qb[s] = *(const f16x8*)(qrow + s * 16 + hi * 8);

  // per-thread staging geometry (identical for K rows and V^T rows)
  const int ch0 = t, ch1 = t + 256;
  const int r0 = ch0 >> 3, g0 = ((ch0 & 7) ^ (r0 & 7)) * 8;
  const int r1 = ch1 >> 3, g1 = ((ch1 & 7) ^ (r1 & 7)) * 8;
  const f16* Kb = KH + base;
  const f16* Vb = VT + base;

  auto STAGE_K = [&](int kt, int buf) {
    const int k0 = kt * 64;
    gload16(Kb + (size_t)(k0 + r0) * DHEAD + g0, (char*)&sK[buf][0] + ch0 * 16);
    gload16(Kb + (size_t)(k0 + r1) * DHEAD + g1, (char*)&sK[buf][0] + ch1 * 16);
  };
  auto STAGE_V = [&](int kt, int buf) {
    const int k0 = kt * 64;
    gload16(Vb + (size_t)r0 * LKK + k0 + g0, (char*)&sVT[buf][0] + ch0 * 16);
    gload16(Vb + (size_t)r1 * LKK + k0 + g1, (char*)&sVT[buf][0] + ch1 * 16);
  };

  float m_r = -1e30f;
  f32x16 oacc0 = {}, oacc1 = {}, oaccL = {};
  const float c1 = 0.125f * LOG2E;
  f16x8 ones;
#pragma unroll
  for (int e = 0; e < 8; ++e) ones[e] = (f16)1.0f;

  auto QK = [&](int kt, f32x16& sa0, f32x16& sa1) {
    const char* sKb = (const char*)&sK[kt & 1][0];
    __builtin_amdgcn_s_setprio(1);
#pragma unroll
    for (int s = 0; s < 4; ++s) {
      f16x8 k0 = *(const f16x8*)(sKb + ((lq * 128 + s * 32 + hi * 16) ^ ((lq & 7) << 4)));
      f16x8 k1 = *(const f16x8*)(sKb + (((32 + lq) * 128 + s * 32 + hi * 16) ^ ((lq & 7) << 4)));
      sa0 = MFMA32(k0, qb[s], sa0);
      sa1 = MFMA32(k1, qb[s], sa1);
    }
    __builtin_amdgcn_s_setprio(0);
  };

  auto SOFTPV = [&](int kt, f32x16& sa0, f32x16& sa1) {
    float p_[32];
#pragma unroll
    for (int r = 0; r < 16; ++r) { p_[r] = sa0[r]; p_[16 + r] = sa1[r]; }

    // scale + bias + mask penalty (log2 domain): k = kt*64 + tt*32 + j*8 + hi*4 + e
#pragma unroll
    for (int u = 0; u < 8; ++u) {
      int tt = u >> 2, j = u & 3;
      int kbase = kt * 64 + tt * 32 + j * 8 + hi * 4;
      f32x4 pen4 = *(const f32x4*)&sPen[kbase];
      int bidx0 = (q0w + lq) - kbase + 2052;
#pragma unroll
      for (int e = 0; e < 4; ++e) {
        float bp = sBias[bidx0 - e] + pen4[e];
        int r = tt * 16 + j * 4 + e;
        p_[r] = p_[r] * c1 + bp;
      }
    }

    // row max: max3 triples + cross-half exchange
    float mm[11];
#pragma unroll
    for (int r = 0; r < 10; ++r) mm[r] = fmax3(p_[3 * r], p_[3 * r + 1], p_[3 * r + 2]);
    mm[10] = fmaxf(p_[30], p_[31]);
    float a0 = fmax3(mm[0], mm[1], mm[2]);
    float a1 = fmax3(mm[3], mm[4], mm[5]);
    float a2 = fmax3(mm[6], mm[7], mm[8]);
    float a3 = fmax3(mm[9], mm[10], a0);
    float mx = fmax3(a1, a2, a3);
    mx = fmaxf(mx, __shfl_xor(mx, 32));

    // defer-max rescale (THR=8 in log2 domain)
    if (__any(mx > m_r + 8.0f)) {
      float mnew = fmaxf(m_r, mx);
      float al = ex2(m_r - mnew);
      m_r = mnew;
#pragma unroll
      for (int r = 0; r < 16; ++r) { oacc0[r] *= al; oacc1[r] *= al; oaccL[r] *= al; }
    }

#pragma unroll
    for (int r = 0; r < 32; ++r) p_[r] = ex2(p_[r] - m_r);

    // pack P -> f16 B-frags via cvt_pk + permlane32_swap (T12)
    f16x8 pf[4];
#pragma unroll
    for (int sl = 0; sl < 4; ++sl) {
      int tt = sl >> 1, sp = sl & 1;
      int bA = tt * 16 + (2 * sp) * 4, bB = tt * 16 + (2 * sp + 1) * 4;
      u32 A0 = pkr(p_[bA], p_[bA + 1]);
      u32 A1 = pkr(p_[bA + 2], p_[bA + 3]);
      u32 B0 = pkr(p_[bB], p_[bB + 1]);
      u32 B1 = pkr(p_[bB + 2], p_[bB + 3]);
      asm volatile("v_permlane32_swap_b32 %0, %1" : "+v"(A0), "+v"(B0));
      asm volatile("v_permlane32_swap_b32 %0, %1" : "+v"(A1), "+v"(B1));
      union { u32 u[4]; f16x8 v; } c;
      c.u[0] = A0; c.u[1] = A1; c.u[2] = B0; c.u[3] = B1;
      pf[sl] = c.v;
    }

    // O^T += V^T * P (rows = d); l-row via ones-MFMA on the matrix pipe
    const char* sVb = (const char*)&sVT[kt & 1][0];
    __builtin_amdgcn_s_setprio(1);
#pragma unroll
    for (int sl = 0; sl < 4; ++sl) {
      int K0 = sl * 16;
      f16x8 v0 = *(const f16x8*)(sVb + ((lq * 128 + K0 * 2 + hi * 16) ^ ((lq & 7) << 4)));
      f16x8 v1 = *(const f16x8*)(sVb + (((32 + lq) * 128 + K0 * 2 + hi * 16) ^ ((lq & 7) << 4)));
      oacc0 = MFMA32(v0, pf[sl], oacc0);
      oacc1 = MFMA32(v1, pf[sl], oacc1);
      oaccL = MFMA32(ones, pf[sl], oaccL);
    }
    __builtin_amdgcn_s_setprio(0);
  };

  // prologue: K(0),V(0),K(1) staged; QK(0) computed
  STAGE_K(0, 0);
  STAGE_V(0, 0);
  STAGE_K(1, 1);
  __syncthreads();
  f32x16 sA0 = {}, sA1 = {}, sB0 = {}, sB1 = {};
  QK(0, sA0, sA1);

  for (int kt = 0; kt < 32; kt += 2) {
    // even half: current S in (sA0,sA1); compute QK(kt+1) into (sB0,sB1)
    if (kt + 2 < 32) STAGE_K(kt + 2, 0);
    STAGE_V(kt + 1, 1);
    sB0 = f32x16{}; sB1 = f32x16{};
    QK(kt + 1, sB0, sB1);
    SOFTPV(kt, sA0, sA1);
    __syncthreads();
    // odd half: current S in (sB0,sB1); compute QK(kt+2) into (sA0,sA1)
    if (kt + 3 < 32) STAGE_K(kt + 3, 1);
    if (kt + 2 < 32) {
      STAGE_V(kt + 2, 0);
      sA0 = f32x16{}; sA1 = f32x16{};
      QK(kt + 2, sA0, sA1);
    }
    SOFTPV(kt + 1, sB0, sB1);
    __syncthreads();
  }

  // normalize + store (lane owns q-row; d from reg pattern); l = any row of oaccL
  const float rinv = 1.0f / oaccL[0];
  const size_t orow = ((size_t)b * LQ + (q0w + lq)) * D_MODEL + h * DHEAD;
#pragma unroll
  for (int dh = 0; dh < 2; ++dh)
#pragma unroll
    for (int j = 0; j < 4; ++j) {
      int d0 = dh * 32 + j * 8 + hi * 4;
      f16x4 ov;
#pragma unroll
      for (int e = 0; e < 4; ++e) {
        float x = (dh ? oacc1[j * 4 + e] : oacc0[j * 4 + e]) * rinv;
        ov[e] = (f16)x;
      }
      *(f16x4*)(O16 + orow + d0) = ov;
    }
}

// ---------------- launch ----------------
extern "C" void kernel_launch(void* const* d_in, const int* in_sizes, int n_in,
                              void* d_out, int out_size, void* d_ws, size_t ws_size,
                              hipStream_t stream) {
  (void)in_sizes; (void)n_in; (void)out_size;
  const float* q   = (const float*)d_in[0];
  const float* k   = (const float*)d_in[1];
  const float* v   = (const float*)d_in[2];
  const void*  msk = d_in[3];
  const float* Wq  = (const float*)d_in[4];
  const float* Wk  = (const float*)d_in[5];
  const float* Wv  = (const float*)d_in[6];
  const float* Wo  = (const float*)d_in[7];
  const float* rel = (const float*)d_in[8];

  char* ws = (char*)d_ws;
  const size_t SL = (size_t)8 << 20;
  const bool bigA = ws_size >= 8 * SL;

  f16 *Xq, *Xk, *Xv, *QHp, *KHp, *VTp, *O16, *W16; char* misc;
  if (bigA) {
    Xq = (f16*)(ws + 0 * SL); Xk = (f16*)(ws + 1 * SL); Xv = (f16*)(ws + 2 * SL);
    QHp = (f16*)(ws + 3 * SL); KHp = (f16*)(ws + 4 * SL); VTp = (f16*)(ws + 5 * SL);
    W16 = (f16*)(ws + 6 * SL); O16 = (f16*)(ws + 2 * SL);
    misc = ws + 7 * SL;
  } else {
    Xq = (f16*)(ws + 0 * SL); Xk = (f16*)(ws + 1 * SL); Xv = (f16*)(ws + 2 * SL);
    QHp = (f16*)(ws + 3 * SL); KHp = (f16*)(ws + 0 * SL); VTp = (f16*)(ws + 1 * SL);
    W16 = (f16*)(ws + 4 * SL); O16 = (f16*)(ws + 2 * SL);
    misc = ws + 5 * SL;
  }
  float* BIAS = (float*)misc;
  unsigned char* M8 = (unsigned char*)(misc + (192 << 10));

  k_prep<<<1, 256, 0, stream>>>(msk, rel, BIAS, M8);
  k_cvt_all<<<16384, 256, 0, stream>>>(q, k, v, Wq, Wk, Wv, Wo, Xq, Xk, Xv, W16);

  if (bigA) {
    k_gemm_qkv<<<dim3(32, 8, 3), 256, 0, stream>>>(Xq, Xk, Xv, W16, QHp, KHp, VTp, 0);
  } else {
    for (int z = 0; z < 3; ++z)
      k_gemm_qkv<<<dim3(32, 8, 1), 256, 0, stream>>>(Xq, Xk, Xv, W16, QHp, KHp, VTp, z);
  }
  k_attn<<<512, 256, 0, stream>>>(QHp, KHp, VTp, BIAS, M8, O16);
  k_gemm_o<<<dim3(32, 16), 256, 0, stream>>>(O16, W16 + 3 * 1048576, (float*)d_out);
}

// Round 6
// 140.783 us; speedup vs baseline: 1.9635x; 1.0813x over previous
//
#include <hip/hip_runtime.h>
#include <math.h>

typedef _Float16 f16;
typedef __fp16 h16x2 __attribute__((ext_vector_type(2)));
typedef _Float16 f16x4 __attribute__((ext_vector_type(4)));
typedef _Float16 f16x8 __attribute__((ext_vector_type(8)));
typedef float f32x4 __attribute__((ext_vector_type(4)));
typedef float f32x16 __attribute__((ext_vector_type(16)));
typedef unsigned int u32;

#define D_MODEL 1024
#define NHEADS 16
#define DHEAD 64
#define LQ 2048
#define LKK 2048
#define BB 2
#define LOG2E 1.4426950408889634f

static __device__ __forceinline__ void gload16(const void* g, void* l) {
  __builtin_amdgcn_global_load_lds(
      (const __attribute__((address_space(1))) u32*)g,
      (__attribute__((address_space(3))) u32*)l, 16, 0, 0);
}
static __device__ __forceinline__ float ex2(float x) {
  float r;
  asm volatile("v_exp_f32 %0, %1\n\ts_nop 0" : "=v"(r) : "v"(x));
  return r;
}
static __device__ __forceinline__ u32 pkr(float a, float b) {
  union { h16x2 h; u32 u; } c;
  c.h = __builtin_amdgcn_cvt_pkrtz(a, b);
  return c.u;
}
static __device__ __forceinline__ float fmax3(float a, float b, float c) {
  return fmaxf(fmaxf(a, b), c);  // clang fuses to v_max3_f32
}
#define MFMA16(a, b, c) __builtin_amdgcn_mfma_f32_16x16x32_f16(a, b, c, 0, 0, 0)
#define MFMA32(a, b, c) __builtin_amdgcn_mfma_f32_32x32x16_f16(a, b, c, 0, 0, 0)

// ---------------- W convert + prep (mask detect/convert, bias table) in one kernel ----------------
__global__ void k_cvtw_prep(const float* Wq, const float* Wk, const float* Wv, const float* Wo,
                            f16* W16, const void* msk, const float* __restrict__ rel,
                            float* __restrict__ biasT, unsigned char* __restrict__ m8) {
  const int blk = blockIdx.x;
  const int t = threadIdx.x;
  if (blk < 4096) {  // W fp32->fp16: 4 x 1M elems = 1M float4
    int i = blk * 256 + t;
    int which = i >> 18, off = i & 262143;
    const float* s = which == 0 ? Wq : (which == 1 ? Wk : (which == 2 ? Wv : Wo));
    float4 x = ((const float4*)s)[off];
    f16x4 o; o[0] = (f16)x.x; o[1] = (f16)x.y; o[2] = (f16)x.z; o[3] = (f16)x.w;
    ((f16x4*)(W16 + (size_t)which * 1048576))[off] = o;
    return;
  }
  if (blk == 4096) {  // mask dtype detect + convert to u8
    __shared__ int o1s, o2s;
    if (t == 0) { o1s = 0; o2s = 0; }
    __syncthreads();
    const unsigned char* raw = (const unsigned char*)msk;
    int o1 = 0, o2 = 0;
    for (int i = t; i < BB * LKK; i += 256) {
      unsigned char vv = raw[i];
      if ((i & 3) && vv) o1 = 1;
      if (((i & 3) == 2) && vv == 0x80u) o2 = 1;
    }
    if (o1) atomicOr(&o1s, 1);
    if (o2) atomicOr(&o2s, 1);
    __syncthreads();
    const int f = o1s ? (o2s ? 2 : 1) : 0;  // 0=int32, 1=bool, 2=f32
    for (int i = t; i < BB * LKK; i += 256) {
      unsigned char v;
      if (f == 0)      v = (((const int*)msk)[i] != 0);
      else if (f == 1) v = (((const unsigned char*)msk)[i] != 0);
      else             v = (((const float*)msk)[i] != 0.0f);
      m8[i] = v;
    }
    return;
  }
  // blk == 4097: bias table, pre-scaled by log2e
  for (int n = t; n < 2048; n += 256) {
    int bucket;
    if (n < 16) bucket = n;
    else {
      float tt = logf((float)n / 16.0f + 1e-9f);  // exact jax op order
      tt = tt / 2.0794415416798357f;
      tt = tt * 16.0f;
      bucket = 16 + (int)tt;
      if (bucket > 31) bucket = 31;
    }
    for (int h = 0; h < NHEADS; ++h)
      biasT[h * 2048 + n] = rel[bucket * NHEADS + h] * LOG2E;
  }
}

// ---------------- GEMM core: C = A[4096,1024] * B[1024,1024]^T, tile 128 x BN ----------------
// AF32: A is fp32, converted (RTE) during reg-staging into LDS (fused cvt).
// EPI 0: f16 scatter into [B,H,L,64].  EPI 1: fp32 row-major.  EPI 2: f16 V^T [B,H,64,L].
template <int EPI, int BN, bool AF32>
static __device__ __forceinline__ void gemm_core(const void* __restrict__ Av,
                                                 const f16* __restrict__ Bm,
                                                 void* __restrict__ C) {
  constexpr int JN = BN / 32;  // col frags per wave
  __shared__ __align__(16) f16 sA[128 * 32];
  __shared__ __align__(16) f16 sB[BN * 32];
  const int t = threadIdx.x;
  const int w = t >> 6, lane = t & 63;
  const int lg = lane >> 4, lc = lane & 15;
  const int wr = w >> 1, wc = w & 1;
  const long row0 = (long)blockIdx.x * 128;
  const long col0 = (long)blockIdx.y * BN;
  f32x4 acc[4][JN] = {};

  for (int kk = 0; kk < 1024; kk += 32) {
#pragma unroll
    for (int it = 0; it < 2; ++it) {
      int ch = t + it * 256;          // chunk = 16B of sA, linear (conflict-free b128 writes)
      int r = ch >> 2, kq = ch & 3;
      if constexpr (AF32) {
        const float* src = (const float*)Av + (row0 + r) * 1024 + kk + kq * 8;
        float4 x0 = *(const float4*)src;
        float4 x1 = *(const float4*)(src + 4);
        f16x8 o;
        o[0] = (f16)x0.x; o[1] = (f16)x0.y; o[2] = (f16)x0.z; o[3] = (f16)x0.w;
        o[4] = (f16)x1.x; o[5] = (f16)x1.y; o[6] = (f16)x1.z; o[7] = (f16)x1.w;
        *(f16x8*)((char*)sA + ch * 16) = o;
      } else {
        gload16((const f16*)Av + (row0 + r) * 1024 + kk + kq * 8, (char*)sA + ch * 16);
      }
    }
#pragma unroll
    for (int it = 0; it < BN / 64; ++it) {
      int ch = t + it * 256;
      int r = ch >> 2, kq = ch & 3;
      gload16(Bm + (col0 + r) * 1024 + kk + kq * 8, (char*)sB + ch * 16);
    }
    __syncthreads();
    f16x8 af[4], bf[JN];
#pragma unroll
    for (int i = 0; i < 4; ++i)
      af[i] = *(const f16x8*)&sA[(wr * 64 + i * 16 + lc) * 32 + lg * 8];
#pragma unroll
    for (int j = 0; j < JN; ++j)
      bf[j] = *(const f16x8*)&sB[(wc * (16 * JN) + j * 16 + lc) * 32 + lg * 8];
#pragma unroll
    for (int i = 0; i < 4; ++i)
#pragma unroll
      for (int j = 0; j < JN; ++j)
        acc[i][j] = MFMA16(af[i], bf[j], acc[i][j]);
    __syncthreads();
  }
#pragma unroll
  for (int i = 0; i < 4; ++i)
#pragma unroll
    for (int j = 0; j < JN; ++j) {
      const long rowb = row0 + wr * 64 + i * 16 + lg * 4;  // 4 consecutive rows (r)
      const long col = col0 + wc * (16 * JN) + j * 16 + lc;
      if (EPI == 2) {  // V^T: [b,h,d,l] with f16x4 over l (=r)
        long b = rowb >> 11, l0 = rowb & 2047;
        long h = col >> 6, d = col & 63;
        f16x4 ov;
#pragma unroll
        for (int r = 0; r < 4; ++r) ov[r] = (f16)acc[i][j][r];
        *(f16x4*)((f16*)C + (((b * NHEADS + h) * DHEAD + d) * (long)LKK + l0)) = ov;
      } else {
#pragma unroll
        for (int r = 0; r < 4; ++r) {
          long row = rowb + r;
          float v = acc[i][j][r];
          if (EPI == 0) {
            long b = row >> 11, l = row & 2047;
            long h = col >> 6, d = col & 63;
            ((f16*)C)[(((b * NHEADS + h) * LQ) + l) * DHEAD + d] = (f16)v;
          } else {
            ((float*)C)[row * 1024 + col] = v;
          }
        }
      }
    }
}

__global__ void __launch_bounds__(256, 3)
k_gemm_qkv(const float* __restrict__ q, const float* __restrict__ k, const float* __restrict__ v,
           const f16* __restrict__ W16, f16* __restrict__ QHp, f16* __restrict__ KHp,
           f16* __restrict__ VTp) {
  const int z = blockIdx.z;
  if (z == 2) {
    gemm_core<2, 128, true>(v, W16 + 2 * 1048576, VTp);
  } else {
    const float* A = z == 0 ? q : k;
    f16* C = z == 0 ? QHp : KHp;
    gemm_core<0, 128, true>(A, W16 + (size_t)z * 1048576, C);
  }
}

// 128x64 tile -> grid (32,16) = 512 blocks = 2 blocks/CU
__global__ void __launch_bounds__(256, 2)
k_gemm_o(const f16* __restrict__ A, const f16* __restrict__ Bm, float* __restrict__ C) {
  gemm_core<1, 64, false>(A, Bm, C);
}

// ---------------- flash attention: swapped-QK^T, 32x32 MFMA, software-pipelined ----------------
// 4 warps/block, 32 q-rows/warp. Grid 512 = 16 qchunks x 32 (b,h), XCD-clustered.
__global__ void __launch_bounds__(256, 2)
k_attn(const f16* __restrict__ QH, const f16* __restrict__ KH, const f16* __restrict__ VT,
       const float* __restrict__ BIASg, const unsigned char* __restrict__ M8,
       f16* __restrict__ O16) {
  __shared__ __align__(16) f16 sK[2][64 * 64];   // K tiles, XOR-swizzled rows
  __shared__ __align__(16) f16 sVT[2][64 * 64];  // V^T tiles, XOR-swizzled rows
  __shared__ __align__(16) float sBias[4104];    // bias*log2e, padded for n<0
  __shared__ __align__(16) float sPen[2048];     // mask penalty (log2 domain)

  const int L = blockIdx.x;
  const int bh = (L & 7) * 4 + ((L >> 3) & 3);   // same-bh blocks -> same XCD (L%8 fixed)
  const int qc = L >> 5;
  const int b = bh >> 4, h = bh & 15;
  const int t = threadIdx.x, w = t >> 6, lane = t & 63;
  const int lq = lane & 31;                      // this lane's q (and d-row for PV)
  const int hi = lane >> 5;
  const int q0w = qc * 128 + w * 32;
  const size_t base = (size_t)bh * LKK * DHEAD;

  for (int i = t; i < 4104; i += 256) {
    int n = i - 2052; n = n < 0 ? 0 : (n > 2047 ? 2047 : n);
    sBias[i] = BIASg[h * 2048 + n];
  }
  for (int i = t; i < 2048; i += 256)
    sPen[i] = M8[b * LKK + i] ? 0.0f : -3.0e9f;

  // Q B-frags straight from global: lane holds Q[q=lq][d = s*16 + hi*8 .. +8]
  f16x8 qb[4];
  const f16* qrow = QH + base + (size_t)(q0w + lq) * DHEAD;
#pragma unroll
  for (int s = 0; s < 4; ++s)
    qb[s] = *(const f16x8*)(qrow + s * 16 + hi * 8);

  // per-thread staging geometry (identical for K rows and V^T rows)
  const int ch0 = t, ch1 = t + 256;
  const int r0 = ch0 >> 3, g0 = ((ch0 & 7) ^ (r0 & 7)) * 8;
  const int r1 = ch1 >> 3, g1 = ((ch1 & 7) ^ (r1 & 7)) * 8;
  const f16* Kb = KH + base;
  const f16* Vb = VT + base;

  auto STAGE_K = [&](int kt, int buf) {
    const int k0 = kt * 64;
    gload16(Kb + (size_t)(k0 + r0) * DHEAD + g0, (char*)&sK[buf][0] + ch0 * 16);
    gload16(Kb + (size_t)(k0 + r1) * DHEAD + g1, (char*)&sK[buf][0] + ch1 * 16);
  };
  auto STAGE_V = [&](int kt, int buf) {
    const int k0 = kt * 64;
    gload16(Vb + (size_t)r0 * LKK + k0 + g0, (char*)&sVT[buf][0] + ch0 * 16);
    gload16(Vb + (size_t)r1 * LKK + k0 + g1, (char*)&sVT[buf][0] + ch1 * 16);
  };

  float m_r = -1e30f;
  f32x16 oacc0 = {}, oacc1 = {}, oaccL = {};
  const float c1 = 0.125f * LOG2E;
  f16x8 ones;
#pragma unroll
  for (int e = 0; e < 8; ++e) ones[e] = (f16)1.0f;

  auto QK = [&](int kt, f32x16& sa0, f32x16& sa1) {
    const char* sKb = (const char*)&sK[kt & 1][0];
    __builtin_amdgcn_s_setprio(1);
#pragma unroll
    for (int s = 0; s < 4; ++s) {
      f16x8 k0 = *(const f16x8*)(sKb + ((lq * 128 + s * 32 + hi * 16) ^ ((lq & 7) << 4)));
      f16x8 k1 = *(const f16x8*)(sKb + (((32 + lq) * 128 + s * 32 + hi * 16) ^ ((lq & 7) << 4)));
      sa0 = MFMA32(k0, qb[s], sa0);
      sa1 = MFMA32(k1, qb[s], sa1);
    }
    __builtin_amdgcn_s_setprio(0);
  };

  auto SOFTPV = [&](int kt, f32x16& sa0, f32x16& sa1) {
    float p_[32];
#pragma unroll
    for (int r = 0; r < 16; ++r) { p_[r] = sa0[r]; p_[16 + r] = sa1[r]; }

    // scale + bias + mask penalty (log2 domain): k = kt*64 + tt*32 + j*8 + hi*4 + e
#pragma unroll
    for (int u = 0; u < 8; ++u) {
      int tt = u >> 2, j = u & 3;
      int kbase = kt * 64 + tt * 32 + j * 8 + hi * 4;
      f32x4 pen4 = *(const f32x4*)&sPen[kbase];
      int bidx0 = (q0w + lq) - kbase + 2052;
#pragma unroll
      for (int e = 0; e < 4; ++e) {
        float bp = sBias[bidx0 - e] + pen4[e];
        int r = tt * 16 + j * 4 + e;
        p_[r] = p_[r] * c1 + bp;
      }
    }

    // row max: max3 triples + cross-half exchange
    float mm[11];
#pragma unroll
    for (int r = 0; r < 10; ++r) mm[r] = fmax3(p_[3 * r], p_[3 * r + 1], p_[3 * r + 2]);
    mm[10] = fmaxf(p_[30], p_[31]);
    float a0 = fmax3(mm[0], mm[1], mm[2]);
    float a1 = fmax3(mm[3], mm[4], mm[5]);
    float a2 = fmax3(mm[6], mm[7], mm[8]);
    float a3 = fmax3(mm[9], mm[10], a0);
    float mx = fmax3(a1, a2, a3);
    mx = fmaxf(mx, __shfl_xor(mx, 32));

    // defer-max rescale (THR=8 in log2 domain)
    if (__any(mx > m_r + 8.0f)) {
      float mnew = fmaxf(m_r, mx);
      float al = ex2(m_r - mnew);
      m_r = mnew;
#pragma unroll
      for (int r = 0; r < 16; ++r) { oacc0[r] *= al; oacc1[r] *= al; oaccL[r] *= al; }
    }

#pragma unroll
    for (int r = 0; r < 32; ++r) p_[r] = ex2(p_[r] - m_r);

    // pack P -> f16 B-frags via cvt_pk + permlane32_swap (T12)
    f16x8 pf[4];
#pragma unroll
    for (int sl = 0; sl < 4; ++sl) {
      int tt = sl >> 1, sp = sl & 1;
      int bA = tt * 16 + (2 * sp) * 4, bB = tt * 16 + (2 * sp + 1) * 4;
      u32 A0 = pkr(p_[bA], p_[bA + 1]);
      u32 A1 = pkr(p_[bA + 2], p_[bA + 3]);
      u32 B0 = pkr(p_[bB], p_[bB + 1]);
      u32 B1 = pkr(p_[bB + 2], p_[bB + 3]);
      asm volatile("v_permlane32_swap_b32 %0, %1" : "+v"(A0), "+v"(B0));
      asm volatile("v_permlane32_swap_b32 %0, %1" : "+v"(A1), "+v"(B1));
      union { u32 u[4]; f16x8 v; } c;
      c.u[0] = A0; c.u[1] = A1; c.u[2] = B0; c.u[3] = B1;
      pf[sl] = c.v;
    }

    // O^T += V^T * P (rows = d); l-row via ones-MFMA on the matrix pipe
    const char* sVb = (const char*)&sVT[kt & 1][0];
    __builtin_amdgcn_s_setprio(1);
#pragma unroll
    for (int sl = 0; sl < 4; ++sl) {
      int K0 = sl * 16;
      f16x8 v0 = *(const f16x8*)(sVb + ((lq * 128 + K0 * 2 + hi * 16) ^ ((lq & 7) << 4)));
      f16x8 v1 = *(const f16x8*)(sVb + (((32 + lq) * 128 + K0 * 2 + hi * 16) ^ ((lq & 7) << 4)));
      oacc0 = MFMA32(v0, pf[sl], oacc0);
      oacc1 = MFMA32(v1, pf[sl], oacc1);
      oaccL = MFMA32(ones, pf[sl], oaccL);
    }
    __builtin_amdgcn_s_setprio(0);
  };

  // prologue: K(0),V(0),K(1) staged; QK(0) computed
  STAGE_K(0, 0);
  STAGE_V(0, 0);
  STAGE_K(1, 1);
  __syncthreads();
  f32x16 sA0 = {}, sA1 = {}, sB0 = {}, sB1 = {};
  QK(0, sA0, sA1);

  for (int kt = 0; kt < 32; kt += 2) {
    // even half: current S in (sA0,sA1); compute QK(kt+1) into (sB0,sB1)
    if (kt + 2 < 32) STAGE_K(kt + 2, 0);
    STAGE_V(kt + 1, 1);
    sB0 = f32x16{}; sB1 = f32x16{};
    QK(kt + 1, sB0, sB1);
    SOFTPV(kt, sA0, sA1);
    __syncthreads();
    // odd half: current S in (sB0,sB1); compute QK(kt+2) into (sA0,sA1)
    if (kt + 3 < 32) STAGE_K(kt + 3, 1);
    if (kt + 2 < 32) {
      STAGE_V(kt + 2, 0);
      sA0 = f32x16{}; sA1 = f32x16{};
      QK(kt + 2, sA0, sA1);
    }
    SOFTPV(kt + 1, sB0, sB1);
    __syncthreads();
  }

  // normalize + store (lane owns q-row; d from reg pattern); l = any row of oaccL
  const float rinv = 1.0f / oaccL[0];
  const size_t orow = ((size_t)b * LQ + (q0w + lq)) * D_MODEL + h * DHEAD;
#pragma unroll
  for (int dh = 0; dh < 2; ++dh)
#pragma unroll
    for (int j = 0; j < 4; ++j) {
      int d0 = dh * 32 + j * 8 + hi * 4;
      f16x4 ov;
#pragma unroll
      for (int e = 0; e < 4; ++e) {
        float x = (dh ? oacc1[j * 4 + e] : oacc0[j * 4 + e]) * rinv;
        ov[e] = (f16)x;
      }
      *(f16x4*)(O16 + orow + d0) = ov;
    }
}

// ---------------- launch ----------------
extern "C" void kernel_launch(void* const* d_in, const int* in_sizes, int n_in,
                              void* d_out, int out_size, void* d_ws, size_t ws_size,
                              hipStream_t stream) {
  (void)in_sizes; (void)n_in; (void)out_size; (void)ws_size;
  const float* q   = (const float*)d_in[0];
  const float* k   = (const float*)d_in[1];
  const float* v   = (const float*)d_in[2];
  const void*  msk = d_in[3];
  const float* Wq  = (const float*)d_in[4];
  const float* Wk  = (const float*)d_in[5];
  const float* Wv  = (const float*)d_in[6];
  const float* Wo  = (const float*)d_in[7];
  const float* rel = (const float*)d_in[8];

  char* ws = (char*)d_ws;
  const size_t SL = (size_t)8 << 20;       // 8 MiB slabs
  f16* QHp = (f16*)(ws + 0 * SL);
  f16* KHp = (f16*)(ws + 1 * SL);
  f16* VTp = (f16*)(ws + 2 * SL);
  f16* O16 = (f16*)(ws + 3 * SL);
  f16* W16 = (f16*)(ws + 4 * SL);          // 4 x 1M f16 = 8 MB
  char* misc = ws + 5 * SL;
  float* BIAS = (float*)misc;              // 16*2048 f32 = 128 KB
  unsigned char* M8 = (unsigned char*)(misc + (192 << 10));

  k_cvtw_prep<<<4098, 256, 0, stream>>>(Wq, Wk, Wv, Wo, W16, msk, rel, BIAS, M8);
  k_gemm_qkv<<<dim3(32, 8, 3), 256, 0, stream>>>(q, k, v, W16, QHp, KHp, VTp);
  k_attn<<<512, 256, 0, stream>>>(QHp, KHp, VTp, BIAS, M8, O16);
  k_gemm_o<<<dim3(32, 16), 256, 0, stream>>>(O16, W16 + 3 * 1048576, (float*)d_out);
}